// Round 6
// baseline (430.593 us; speedup 1.0000x reference)
//
#include <hip/hip_runtime.h>
#include <math.h>

#define N_ROWS 32768
#define D 256
#define C 16

// workspace layout in floats
#define WS_SUMS_A 0
#define WS_SQ_A   4096
#define WS_SUMS_B 8192
#define WS_SQ_B   12288
#define WS_INV    16384
#define WS_COV    16385
#define WS_COUNTS 16392   /* int[16] */
#define WS_CURSOR 16408   /* int[16] */
#define WS_POFFP  16424   /* int[17] 32-row substep offsets */
#define WS_EOFF   16448   /* int[17] row prefix */
#define WS_PERM   16640   /* int[32768] */
#define WS_ZERO_FLOATS 16408

#define WS_PSUM   49408   /* [8 split][16 cls][2 inp][2 stat][256] = 131072 f32 */
#define WS_GPART  180480
#define GP_TILE   16384
#define GP_PER_SPLIT (3 * C * 2 * GP_TILE)   /* 1,572,864 floats */
#define NSPLIT    8
#define NEED_A ((size_t)(WS_GPART + NSPLIT * GP_PER_SPLIT) * 4)   /* ~48.7 MiB */

typedef __attribute__((ext_vector_type(8))) __bf16 bf16x8;
typedef __attribute__((ext_vector_type(16))) float f32x16;

__device__ inline unsigned bf16_rne(float f) {
    unsigned u = __float_as_uint(f);
    return (u + 0x7fffu + ((u >> 16) & 1u)) >> 16;
}
__device__ inline unsigned pack_bf16(float lo, float hi) {
    return bf16_rne(lo) | (bf16_rne(hi) << 16);
}

__global__ __launch_bounds__(256) void k_hist(const int* __restrict__ labels,
                                              int* __restrict__ counts) {
    __shared__ int h[C];
    const int t = threadIdx.x;
    if (t < C) h[t] = 0;
    __syncthreads();
    const int i = blockIdx.x * 256 + t;
    atomicAdd(&h[labels[i]], 1);
    __syncthreads();
    if (t < C) atomicAdd(&counts[t], h[t]);
}

__global__ void k_scan(const int* __restrict__ counts, int* __restrict__ cursor,
                       int* __restrict__ poffp, int* __restrict__ eoffp) {
    if (threadIdx.x == 0) {
        int off = 0, po = 0;
        for (int c = 0; c < C; ++c) {
            cursor[c] = off;
            eoffp[c] = off;
            poffp[c] = po;
            off += counts[c];
            po += (counts[c] + 31) >> 5;
        }
        poffp[C] = po;
        eoffp[C] = off;
    }
}

__global__ __launch_bounds__(256) void k_scatter(const int* __restrict__ labels,
                                                 int* __restrict__ cursor,
                                                 int* __restrict__ perm) {
    __shared__ int lh[C];
    __shared__ int lbase[C];
    const int t = threadIdx.x;
    if (t < C) lh[t] = 0;
    __syncthreads();
    const int i = blockIdx.x * 256 + t;
    const int lab = labels[i];
    const int lr = atomicAdd(&lh[lab], 1);
    __syncthreads();
    if (t < C) lbase[t] = atomicAdd(&cursor[t], lh[t]);
    __syncthreads();
    perm[lbase[lab] + lr] = i;
}

// Streaming inv_loss: mean((za-zb)^2) partials. Pure float4 stream.
__global__ __launch_bounds__(256) void k_inv(const float* __restrict__ za,
                                             const float* __restrict__ zb,
                                             float* __restrict__ ws) {
    const int t = threadIdx.x;
    const int idx = blockIdx.x * 256 + t;
    const int stride = gridDim.x * 256;
    float acc = 0.f;
    for (int i = idx; i < N_ROWS * D / 4; i += stride) {
        const float4 a = ((const float4*)za)[i];
        const float4 b = ((const float4*)zb)[i];
        const float dx = a.x - b.x, dy = a.y - b.y;
        const float dz = a.z - b.z, dw = a.w - b.w;
        acc += dx * dx + dy * dy + dz * dz + dw * dw;
    }
    for (int o = 32; o > 0; o >>= 1) acc += __shfl_down(acc, o, 64);
    if ((t & 63) == 0) atomicAdd(&ws[WS_INV], acc);
}

// Fused gather + bf16 pack + split-K MFMA Gram (+ class stats on tile01).
// Thread = column; 32 coalesced 256B row-loads per substep straight to regs;
// XOR-swizzled LDS image (<=2-way banks on write and frag read); register
// prefetch of substep s+1 issued before MFMA(s).
__global__ __launch_bounds__(256) void k_gram2(const float* __restrict__ za,
                                               const float* __restrict__ zb,
                                               const int* __restrict__ perm,
                                               const int* __restrict__ counts,
                                               const int* __restrict__ poffp,
                                               const int* __restrict__ eoffp,
                                               float* __restrict__ ws) {
    const int t = threadIdx.x;
    const int tile = blockIdx.x >> 3;        // 0:(0,0) 1:(0,1) 2:(1,1)
    const int split = blockIdx.x & 7;
    const int tx = tile >> 1, ty = (tile + 1) >> 1;
    const int cls = blockIdx.y, inp = blockIdx.z;
    const float* X = inp ? zb : za;
    const int cnt = counts[cls];
    const int eoff = eoffp[cls];
    const int nsteps = poffp[cls + 1] - poffp[cls];
    const int chunk = (nsteps + NSPLIT - 1) / NSPLIT;
    const int sb = split * chunk;
    const int se = min(sb + chunk, nsteps);
    const bool diag = (tx == ty);
    const int cm0 = tx * 128, cn0 = ty * 128;

    __shared__ __align__(16) unsigned img[2][2560];   // 20.5 KB
    __shared__ int ridx[320];

    const int nl = (se > sb) ? (se - sb) * 32 : 0;
    for (int i = t; i < nl; i += 256) {
        const int gr = sb * 32 + i;
        ridx[i] = (gr < cnt) ? perm[eoff + gr] : -1;
    }
    __syncthreads();

    const int lane = t & 63, w = t >> 6;
    const int wr = w & 1, wc = w >> 1;
    const int cg = lane & 31, q = lane >> 5;

    // staging ownership
    const int ci = t & 127;
    const int h2 = t >> 7;                      // diag: k-half; tile01: image sel
    const int gcol = diag ? (cm0 + ci) : (h2 ? cn0 + ci : cm0 + ci);
    const int kofs = diag ? 16 * h2 : 0;
    const int xsw = ((ci >> 2) ^ (ci >> 5)) & 3;

    f32x16 acc[2][2];
    #pragma unroll
    for (int i = 0; i < 2; ++i)
        #pragma unroll
        for (int j = 0; j < 2; ++j) acc[i][j] = 0.0f;

    float s1 = 0.f, s2 = 0.f;
    float v[32];

    auto loadv = [&](int s) {
        const int base = (s - sb) * 32 + kofs;
        if (diag) {
            #pragma unroll
            for (int k = 0; k < 16; ++k) {
                const int ri = ridx[base + k];
                v[k] = (ri >= 0) ? X[(size_t)ri * D + gcol] : 0.f;
            }
        } else {
            #pragma unroll
            for (int k = 0; k < 32; ++k) {
                const int ri = ridx[base + k];
                v[k] = (ri >= 0) ? X[(size_t)ri * D + gcol] : 0.f;
            }
        }
    };

    if (se > sb) loadv(sb);
    for (int s = sb; s < se; ++s) {
        unsigned pw[16];
        if (diag) {
            #pragma unroll
            for (int d = 0; d < 8; ++d) pw[d] = pack_bf16(v[2 * d], v[2 * d + 1]);
        } else {
            #pragma unroll
            for (int d = 0; d < 16; ++d) pw[d] = pack_bf16(v[2 * d], v[2 * d + 1]);
            #pragma unroll
            for (int k = 0; k < 32; ++k) { s1 += v[k]; s2 += v[k] * v[k]; }
        }
        __syncthreads();    // previous MFMA frag reads done
        if (diag) {
            const int j0 = 2 * h2;
            *(uint4*)&img[0][ci * 20 + 4 * ((j0)     ^ xsw)] = make_uint4(pw[0], pw[1], pw[2], pw[3]);
            *(uint4*)&img[0][ci * 20 + 4 * ((j0 + 1) ^ xsw)] = make_uint4(pw[4], pw[5], pw[6], pw[7]);
        } else {
            #pragma unroll
            for (int j = 0; j < 4; ++j)
                *(uint4*)&img[h2][ci * 20 + 4 * (j ^ xsw)] =
                    make_uint4(pw[4 * j], pw[4 * j + 1], pw[4 * j + 2], pw[4 * j + 3]);
        }
        if (s + 1 < se) loadv(s + 1);   // in flight across barrier + MFMA
        __syncthreads();
        const int bch = diag ? 0 : 1;
        #pragma unroll
        for (int h = 0; h < 2; ++h) {
            bf16x8 a[2], b[2];
            #pragma unroll
            for (int i = 0; i < 2; ++i) {
                const int colA = wr * 64 + i * 32 + cg;
                const int xa = ((colA >> 2) ^ (colA >> 5)) & 3;
                a[i] = *(const bf16x8*)&img[0][colA * 20 + 4 * ((2 * h + q) ^ xa)];
                const int colB = wc * 64 + i * 32 + cg;
                const int xb = ((colB >> 2) ^ (colB >> 5)) & 3;
                b[i] = *(const bf16x8*)&img[bch][colB * 20 + 4 * ((2 * h + q) ^ xb)];
            }
            acc[0][0] = __builtin_amdgcn_mfma_f32_32x32x16_bf16(a[0], b[0], acc[0][0], 0, 0, 0);
            acc[0][1] = __builtin_amdgcn_mfma_f32_32x32x16_bf16(a[0], b[1], acc[0][1], 0, 0, 0);
            acc[1][0] = __builtin_amdgcn_mfma_f32_32x32x16_bf16(a[1], b[0], acc[1][0], 0, 0, 0);
            acc[1][1] = __builtin_amdgcn_mfma_f32_32x32x16_bf16(a[1], b[1], acc[1][1], 0, 0, 0);
        }
    }

    // split-K partial out (no atomics)
    float* gp = ws + WS_GPART + (size_t)split * GP_PER_SPLIT
              + ((size_t)tile * C * 2 + cls * 2 + inp) * GP_TILE;
    #pragma unroll
    for (int i = 0; i < 2; ++i)
        #pragma unroll
        for (int j = 0; j < 2; ++j)
            #pragma unroll
            for (int r = 0; r < 16; ++r) {
                const int row = wr * 64 + i * 32 + (r & 3) + 8 * (r >> 2) + 4 * q;
                const int col = wc * 64 + j * 32 + cg;
                gp[row * 128 + col] = acc[i][j][r];
            }

    if (tile == 1) {   // tile01 covered every (row,col) of this (cls,inp,split)
        const size_t slot = ((size_t)split * C + cls) * 2 + inp;
        ws[WS_PSUM + slot * 512 + t]       = s1;
        ws[WS_PSUM + slot * 512 + 256 + t] = s2;
    }
}

// Fold per-(split) stat partials into class stats.
__global__ __launch_bounds__(256) void k_reduce2(float* __restrict__ ws) {
    const int t = threadIdx.x;
    const int c = blockIdx.x;
    const int stat = blockIdx.y & 1, inp = blockIdx.y >> 1;
    float acc = 0.f;
    #pragma unroll
    for (int sp = 0; sp < NSPLIT; ++sp)
        acc += ws[WS_PSUM + (((size_t)sp * C + c) * 2 + inp) * 512 + stat * 256 + t];
    const int base = stat ? (inp ? WS_SQ_B : WS_SQ_A)
                          : (inp ? WS_SUMS_B : WS_SUMS_A);
    ws[base + c * D + t] = acc;
}

// Sum split partials, form cov, accumulate weighted off-diagonal cov^2.
__global__ __launch_bounds__(256) void k_cov(const int* __restrict__ counts,
                                             float* __restrict__ ws) {
    const int t = threadIdx.x;
    const int tile = blockIdx.x;
    const int tx = tile >> 1, ty = (tile + 1) >> 1;
    const int cls = blockIdx.y, inp = blockIdx.z;
    const int cnt = counts[cls];
    const float fc = (float)cnt;
    const float cinv = 1.f / fc, uinv = 1.f / (fc - 1.f);
    const float wgt = (tx == ty) ? 1.f : 2.f;
    const int cm0 = tx * 128, cn0 = ty * 128;
    __shared__ float M[D];
    const float* sums = ws + (inp ? WS_SUMS_B : WS_SUMS_A) + cls * D;
    M[t] = sums[t] * cinv;
    __syncthreads();

    const float* gp0 = ws + WS_GPART + ((size_t)tile * C * 2 + cls * 2 + inp) * GP_TILE;
    float local = 0.f;
    #pragma unroll 4
    for (int k = 0; k < 64; ++k) {
        const int e = k * 256 + t;
        float g = 0.f;
        #pragma unroll
        for (int s = 0; s < NSPLIT; ++s)
            g += gp0[(size_t)s * GP_PER_SPLIT + e];
        const int row = e >> 7, col = e & 127;
        const int gm = cm0 + row, gn = cn0 + col;
        const float cov = (g - fc * M[gm] * M[gn]) * uinv;
        if (gm != gn) local += wgt * cov * cov;
    }
    for (int o = 32; o > 0; o >>= 1) local += __shfl_down(local, o, 64);
    __shared__ float red[4];
    if ((t & 63) == 0) red[t >> 6] = local;
    __syncthreads();
    if (t == 0) atomicAdd(&ws[WS_COV], red[0] + red[1] + red[2] + red[3]);
}

// ---------------- fallback (tiny ws): round-2 kernels ----------------
__global__ __launch_bounds__(256) void k_stats(const float* __restrict__ za,
                                               const float* __restrict__ zb,
                                               const int* __restrict__ labels,
                                               float* __restrict__ ws) {
    const int t = threadIdx.x;
    __shared__ float S[4][C * D];
    __shared__ int lab[512];
    for (int i = t; i < 4 * C * D; i += 256) ((float*)S)[i] = 0.f;
    const int r0 = blockIdx.x * 512;
    for (int i = t; i < 512; i += 256) lab[i] = labels[r0 + i];
    __syncthreads();
    float invp = 0.f;
    #pragma unroll 4
    for (int rr = 0; rr < 512; ++rr) {
        const int l = lab[rr];
        const float a = za[(size_t)(r0 + rr) * D + t];
        const float b = zb[(size_t)(r0 + rr) * D + t];
        const float dd = a - b;
        invp += dd * dd;
        S[0][l * D + t] += a;
        S[1][l * D + t] += a * a;
        S[2][l * D + t] += b;
        S[3][l * D + t] += b * b;
    }
    __syncthreads();
    #pragma unroll
    for (int c = 0; c < C; ++c) {
        atomicAdd(&ws[WS_SUMS_A + c * D + t], S[0][c * D + t]);
        atomicAdd(&ws[WS_SQ_A   + c * D + t], S[1][c * D + t]);
        atomicAdd(&ws[WS_SUMS_B + c * D + t], S[2][c * D + t]);
        atomicAdd(&ws[WS_SQ_B   + c * D + t], S[3][c * D + t]);
    }
    for (int o = 32; o > 0; o >>= 1) invp += __shfl_down(invp, o, 64);
    if ((t & 63) == 0) atomicAdd(&ws[WS_INV], invp);
}

#define STR 20
#define KB 32
__global__ __launch_bounds__(256) void k_gram_slow(const float* __restrict__ za,
                                                   const float* __restrict__ zb,
                                                   const int* __restrict__ perm,
                                                   const int* __restrict__ counts,
                                                   float* __restrict__ ws) {
    const int t = threadIdx.x;
    const int tile = blockIdx.x;
    const int tx = tile >> 1, ty = (tile + 1) >> 1;
    const int cls = blockIdx.y;
    const int inp = blockIdx.z;
    const float* X = inp ? zb : za;
    const float* sums = ws + (inp ? WS_SUMS_B : WS_SUMS_A) + cls * D;
    int offs = 0;
    for (int c = 0; c < cls; ++c) offs += counts[c];
    const int cnt = counts[cls];
    const int cm0 = tx * 128, cn0 = ty * 128;
    __shared__ __align__(16) unsigned lds[2][256 * STR];
    const int p = t >> 5, cq = t & 31;
    const int lane = t & 63, w = t >> 6;
    const int wr = w & 1, wc = w >> 1;
    const int cg = lane & 31, q = lane >> 5;
    f32x16 acc[2][2];
    #pragma unroll
    for (int i = 0; i < 2; ++i)
        #pragma unroll
        for (int j = 0; j < 2; ++j) acc[i][j] = 0.0f;
    const int nsteps = (cnt + KB - 1) / KB;
    auto stage = [&](int buf, int k0) {
        #pragma unroll
        for (int ch = 0; ch < 2; ++ch) {
            const int gc = (ch ? cn0 : cm0) + 4 * cq;
            #pragma unroll
            for (int sub = 0; sub < 2; ++sub) {
                const int rr = sub * 16 + 2 * p;
                const int r0 = k0 + rr, r1 = r0 + 1;
                float4 v0 = make_float4(0.f, 0.f, 0.f, 0.f), v1 = v0;
                if (r0 < cnt) v0 = *(const float4*)(X + (size_t)perm[offs + r0] * D + gc);
                if (r1 < cnt) v1 = *(const float4*)(X + (size_t)perm[offs + r1] * D + gc);
                unsigned* dst = &lds[buf][(ch * 128 + 4 * cq) * STR + (rr >> 1)];
                dst[0 * STR] = pack_bf16(v0.x, v1.x);
                dst[1 * STR] = pack_bf16(v0.y, v1.y);
                dst[2 * STR] = pack_bf16(v0.z, v1.z);
                dst[3 * STR] = pack_bf16(v0.w, v1.w);
            }
        }
    };
    auto frag = [&](int buf, int colbase, int h) -> bf16x8 {
        return *(const bf16x8*)&lds[buf][(colbase + cg) * STR + h * 8 + q * 4];
    };
    stage(0, 0);
    for (int s = 0; s < nsteps; ++s) {
        __syncthreads();
        const int buf = s & 1;
        if (s + 1 < nsteps) stage(buf ^ 1, (s + 1) * KB);
        #pragma unroll
        for (int h = 0; h < 2; ++h) {
            bf16x8 a0 = frag(buf, wr * 64, h);
            bf16x8 a1 = frag(buf, wr * 64 + 32, h);
            bf16x8 b0 = frag(buf, 128 + wc * 64, h);
            bf16x8 b1 = frag(buf, 128 + wc * 64 + 32, h);
            acc[0][0] = __builtin_amdgcn_mfma_f32_32x32x16_bf16(a0, b0, acc[0][0], 0, 0, 0);
            acc[0][1] = __builtin_amdgcn_mfma_f32_32x32x16_bf16(a0, b1, acc[0][1], 0, 0, 0);
            acc[1][0] = __builtin_amdgcn_mfma_f32_32x32x16_bf16(a1, b0, acc[1][0], 0, 0, 0);
            acc[1][1] = __builtin_amdgcn_mfma_f32_32x32x16_bf16(a1, b1, acc[1][1], 0, 0, 0);
        }
    }
    const float fc = (float)cnt;
    const float cinv = 1.f / fc, uinv = 1.f / (fc - 1.f);
    const float wgt = (tx == ty) ? 1.f : 2.f;
    float local = 0.f;
    #pragma unroll
    for (int i = 0; i < 2; ++i) {
        #pragma unroll
        for (int j = 0; j < 2; ++j) {
            const int gn = cn0 + wc * 64 + j * 32 + (lane & 31);
            const float mn = sums[gn] * cinv;
            #pragma unroll
            for (int r = 0; r < 16; ++r) {
                const int row = (r & 3) + 8 * (r >> 2) + 4 * q;
                const int gm = cm0 + wr * 64 + i * 32 + row;
                const float cov = (acc[i][j][r] - fc * (sums[gm] * cinv) * mn) * uinv;
                if (gm != gn) local += wgt * cov * cov;
            }
        }
    }
    for (int o = 32; o > 0; o >>= 1) local += __shfl_down(local, o, 64);
    if (lane == 0) atomicAdd(&ws[WS_COV], local);
}

__global__ __launch_bounds__(256) void k_final(const float* __restrict__ ws,
                                               float* __restrict__ out) {
    __shared__ float M[C * D];
    __shared__ float redv[4];
    __shared__ float redp[4];
    const int t = threadIdx.x;
    const int* counts = (const int*)ws + WS_COUNTS;

    float vsum = 0.f;
    for (int idx = t; idx < 2 * C * D; idx += 256) {
        const int inp = idx >> 12;
        const int cd = idx & 4095;
        const int c = cd >> 8;
        const float cnt = (float)counts[c];
        const float s  = ws[(inp ? WS_SUMS_B : WS_SUMS_A) + cd];
        const float sq = ws[(inp ? WS_SQ_B   : WS_SQ_A)   + cd];
        const float mean = s / cnt;
        const float var = (sq - cnt * mean * mean) / (cnt - 1.f);
        vsum += fmaxf(1.f - sqrtf(var + 1e-4f), 0.f);
    }
    for (int cd = t; cd < C * D; cd += 256) {
        const int c = cd >> 8;
        const float cnt = (float)counts[c];
        M[cd] = 0.5f * (ws[WS_SUMS_A + cd] + ws[WS_SUMS_B + cd]) / cnt;
    }
    for (int o = 32; o > 0; o >>= 1) vsum += __shfl_down(vsum, o, 64);
    if ((t & 63) == 0) redv[t >> 6] = vsum;
    __syncthreads();

    const int wv = t >> 6, ln = t & 63;
    float psum = 0.f;
    int p = 0;
    for (int i = 0; i < C; ++i) {
        for (int j = i + 1; j < C; ++j, ++p) {
            if ((p & 3) != wv) continue;
            float d2 = 0.f;
            #pragma unroll
            for (int d = ln; d < D; d += 64) {
                const float df = M[i * D + d] - M[j * D + d];
                d2 += df * df;
            }
            for (int o = 32; o > 0; o >>= 1) d2 += __shfl_down(d2, o, 64);
            if (ln == 0) {
                const float dist = sqrtf(d2);
                const float r = fmaxf(50.f - dist, 0.f);
                psum += r * r;
            }
        }
    }
    if (ln == 0) redp[wv] = psum;
    __syncthreads();

    if (t == 0) {
        const float var_total = redv[0] + redv[1] + redv[2] + redv[3];
        const float var_loss = var_total / 8192.f;
        const float class_sum = redp[0] + redp[1] + redp[2] + redp[3];
        const float class_loss = class_sum / 120.f;
        const float inv_loss = ws[WS_INV] / (float)(N_ROWS * D);
        const float cov_loss = 0.5f * ws[WS_COV] / (float)(C * D);
        out[0] = 25.f * inv_loss + 25.f * var_loss + 1.f * cov_loss + 50.f * class_loss;
    }
}

extern "C" void kernel_launch(void* const* d_in, const int* in_sizes, int n_in,
                              void* d_out, int out_size, void* d_ws, size_t ws_size,
                              hipStream_t stream) {
    const float* za = (const float*)d_in[0];
    const float* zb = (const float*)d_in[1];
    const int* labels = (const int*)d_in[2];
    float* out = (float*)d_out;
    float* ws = (float*)d_ws;
    int* wsi = (int*)d_ws;

    hipMemsetAsync(d_ws, 0, WS_ZERO_FLOATS * sizeof(float), stream);
    k_hist<<<128, 256, 0, stream>>>(labels, wsi + WS_COUNTS);
    k_scan<<<1, 64, 0, stream>>>(wsi + WS_COUNTS, wsi + WS_CURSOR,
                                 wsi + WS_POFFP, wsi + WS_EOFF);
    k_scatter<<<128, 256, 0, stream>>>(labels, wsi + WS_CURSOR, wsi + WS_PERM);

    if (ws_size >= NEED_A) {
        k_inv<<<2048, 256, 0, stream>>>(za, zb, ws);
        k_gram2<<<dim3(3 * NSPLIT, C, 2), 256, 0, stream>>>(
            za, zb, wsi + WS_PERM, wsi + WS_COUNTS, wsi + WS_POFFP,
            wsi + WS_EOFF, ws);
        k_reduce2<<<dim3(C, 4), 256, 0, stream>>>(ws);
        k_cov<<<dim3(3, C, 2), 256, 0, stream>>>(wsi + WS_COUNTS, ws);
    } else {
        k_stats<<<64, 256, 0, stream>>>(za, zb, labels, ws);
        k_gram_slow<<<dim3(3, C, 2), 256, 0, stream>>>(za, zb, wsi + WS_PERM,
                                                       wsi + WS_COUNTS, ws);
    }
    k_final<<<1, 256, 0, stream>>>(ws, out);
}

// Round 7
// 337.538 us; speedup vs baseline: 1.2757x; 1.2757x over previous
//
#include <hip/hip_runtime.h>
#include <math.h>

#define N_ROWS 32768
#define D 256
#define C 16

// workspace layout in floats
#define WS_SUMS_A 0
#define WS_SQ_A   4096
#define WS_SUMS_B 8192
#define WS_SQ_B   12288
#define WS_INV    16384
#define WS_COV    16385
#define WS_COUNTS 16392   /* int[16] */
#define WS_CURSOR 16408   /* int[16] */
#define WS_POFFP  16424   /* int[17] 32-row substep offsets */
#define WS_EOFF   16448   /* int[17] row prefix */
#define WS_PERM   16640   /* int[32768] */
#define WS_ZERO_FLOATS 16408

#define WS_PSUM   49408   /* [8 split][16 cls][2 inp][2 stat][256] = 131072 f32 */
#define WS_GPART  180480
#define GP_TILE   16384
#define GP_PER_SPLIT (3 * C * 2 * GP_TILE)   /* 1,572,864 floats */
#define NSPLIT    8
#define NEED_A ((size_t)(WS_GPART + NSPLIT * GP_PER_SPLIT) * 4)   /* ~48.7 MiB */

typedef __attribute__((ext_vector_type(8))) __bf16 bf16x8;
typedef __attribute__((ext_vector_type(16))) float f32x16;

__device__ inline unsigned bf16_rne(float f) {
    unsigned u = __float_as_uint(f);
    return (u + 0x7fffu + ((u >> 16) & 1u)) >> 16;
}
__device__ inline unsigned pack_bf16(float lo, float hi) {
    return bf16_rne(lo) | (bf16_rne(hi) << 16);
}
// Conflict-free MFMA image: stride 17 (odd -> 32-bank coverage on b128 reads),
// k-rotation by ((c>>5)&3)*4 spreads the write quads; 4-dword blocks stay
// contiguous so bf16x8 frag reads remain single ds_read_b128.
__device__ inline int img_idx(int c, int s) {
    return c * 17 + ((s + ((c >> 3) & 12)) & 15);
}

__global__ __launch_bounds__(256) void k_hist(const int* __restrict__ labels,
                                              int* __restrict__ counts) {
    __shared__ int h[C];
    const int t = threadIdx.x;
    if (t < C) h[t] = 0;
    __syncthreads();
    const int i = blockIdx.x * 256 + t;
    atomicAdd(&h[labels[i]], 1);
    __syncthreads();
    if (t < C) atomicAdd(&counts[t], h[t]);
}

__global__ void k_scan(const int* __restrict__ counts, int* __restrict__ cursor,
                       int* __restrict__ poffp, int* __restrict__ eoffp) {
    if (threadIdx.x == 0) {
        int off = 0, po = 0;
        for (int c = 0; c < C; ++c) {
            cursor[c] = off;
            eoffp[c] = off;
            poffp[c] = po;
            off += counts[c];
            po += (counts[c] + 31) >> 5;
        }
        poffp[C] = po;
        eoffp[C] = off;
    }
}

__global__ __launch_bounds__(256) void k_scatter(const int* __restrict__ labels,
                                                 int* __restrict__ cursor,
                                                 int* __restrict__ perm) {
    __shared__ int lh[C];
    __shared__ int lbase[C];
    const int t = threadIdx.x;
    if (t < C) lh[t] = 0;
    __syncthreads();
    const int i = blockIdx.x * 256 + t;
    const int lab = labels[i];
    const int lr = atomicAdd(&lh[lab], 1);
    __syncthreads();
    if (t < C) lbase[t] = atomicAdd(&cursor[t], lh[t]);
    __syncthreads();
    perm[lbase[lab] + lr] = i;
}

// Streaming inv_loss: mean((za-zb)^2) partials. Pure float4 stream.
__global__ __launch_bounds__(256) void k_inv(const float* __restrict__ za,
                                             const float* __restrict__ zb,
                                             float* __restrict__ ws) {
    const int t = threadIdx.x;
    const int idx = blockIdx.x * 256 + t;
    const int stride = gridDim.x * 256;
    float acc = 0.f;
    for (int i = idx; i < N_ROWS * D / 4; i += stride) {
        const float4 a = ((const float4*)za)[i];
        const float4 b = ((const float4*)zb)[i];
        const float dx = a.x - b.x, dy = a.y - b.y;
        const float dz = a.z - b.z, dw = a.w - b.w;
        acc += dx * dx + dy * dy + dz * dz + dw * dw;
    }
    for (int o = 32; o > 0; o >>= 1) acc += __shfl_down(acc, o, 64);
    if ((t & 63) == 0) atomicAdd(&ws[WS_INV], acc);
}

// Fused gather + bf16 pack + split-K MFMA Gram (+ class stats on tile 1).
// Staging: float2 row-pair loads (512 B per wave instr), packed and written to
// the double-buffered LDS image immediately (no register arrays -> no spill).
__global__ __launch_bounds__(256) void k_gram3(const float* __restrict__ za,
                                               const float* __restrict__ zb,
                                               const int* __restrict__ perm,
                                               const int* __restrict__ counts,
                                               const int* __restrict__ poffp,
                                               const int* __restrict__ eoffp,
                                               float* __restrict__ ws) {
    const int t = threadIdx.x;
    const int tile = blockIdx.x >> 3;        // 0:(0,0) 1:(0,1) 2:(1,1)
    const int split = blockIdx.x & 7;
    const int tx = tile >> 1, ty = (tile + 1) >> 1;
    const int cls = blockIdx.y, inp = blockIdx.z;
    const float* X = inp ? zb : za;
    const int cnt = counts[cls];
    const int eoff = eoffp[cls];
    const int nsteps = poffp[cls + 1] - poffp[cls];
    const int chunk = (nsteps + NSPLIT - 1) / NSPLIT;
    const int sb = split * chunk;
    const int se = min(sb + chunk, nsteps);
    const bool diag = (tx == ty);
    const int cm0 = tx * 128, cn0 = ty * 128;

    __shared__ __align__(16) unsigned img[2][2][2176];   // ~34.8 KB
    __shared__ float sstats[512];                        // 2 KB

    for (int i = t; i < 512; i += 256) sstats[i] = 0.f;

    const int lane = t & 63, w = t >> 6;
    const int wr = w & 1, wc = w >> 1;
    const int cg = lane & 31, q = lane >> 5;

    f32x16 acc[2][2];
    #pragma unroll
    for (int i = 0; i < 2; ++i)
        #pragma unroll
        for (int j = 0; j < 2; ++j) acc[i][j] = 0.0f;

    float s1x = 0.f, s1y = 0.f, s2x = 0.f, s2y = 0.f;

    // staging coords
    const int half = t >> 7;          // tile01: image select
    const int u = t & 127;
    const int cp = u & 63;            // col pair within image
    const int kg2 = u >> 6;           // tile01: k-group (0..1), 8 kp each
    const int kg4 = t >> 6;           // diag: k-group (0..3), 4 kp each

    auto stage = [&](int buf, int s) {
        const int r32 = s * 32;
        if (diag) {
            const int gc = cm0 + 2 * cp;
            #pragma unroll
            for (int it = 0; it < 4; ++it) {
                const int kp = kg4 * 4 + it;
                const int sr0 = r32 + 2 * kp, sr1 = sr0 + 1;
                float2 f0 = make_float2(0.f, 0.f), f1 = f0;
                if (sr0 < cnt) f0 = *(const float2*)(X + (size_t)perm[eoff + sr0] * D + gc);
                if (sr1 < cnt) f1 = *(const float2*)(X + (size_t)perm[eoff + sr1] * D + gc);
                img[buf][0][img_idx(2 * cp,     kp)] = pack_bf16(f0.x, f1.x);
                img[buf][0][img_idx(2 * cp + 1, kp)] = pack_bf16(f0.y, f1.y);
            }
        } else {
            const int gc = (half ? cn0 : cm0) + 2 * cp;
            #pragma unroll
            for (int it = 0; it < 8; ++it) {
                const int kp = kg2 * 8 + it;
                const int sr0 = r32 + 2 * kp, sr1 = sr0 + 1;
                float2 f0 = make_float2(0.f, 0.f), f1 = f0;
                if (sr0 < cnt) f0 = *(const float2*)(X + (size_t)perm[eoff + sr0] * D + gc);
                if (sr1 < cnt) f1 = *(const float2*)(X + (size_t)perm[eoff + sr1] * D + gc);
                img[buf][half][img_idx(2 * cp,     kp)] = pack_bf16(f0.x, f1.x);
                img[buf][half][img_idx(2 * cp + 1, kp)] = pack_bf16(f0.y, f1.y);
                if (tile == 1) {   // stats: tile 1 covers every (row,col) once
                    s1x += f0.x + f1.x;  s2x += f0.x * f0.x + f1.x * f1.x;
                    s1y += f0.y + f1.y;  s2y += f0.y * f0.y + f1.y * f1.y;
                }
            }
        }
    };

    const int bch = diag ? 0 : 1;
    if (sb < se) {
        stage(0, sb);
        __syncthreads();
        for (int s = sb; s < se; ++s) {
            const int buf = (s - sb) & 1;
            if (s + 1 < se) stage(buf ^ 1, s + 1);   // writes other buffer
            #pragma unroll
            for (int h = 0; h < 2; ++h) {
                bf16x8 a[2], b[2];
                #pragma unroll
                for (int i = 0; i < 2; ++i) {
                    a[i] = *(const bf16x8*)&img[buf][0][img_idx(wr * 64 + i * 32 + cg, h * 8 + q * 4)];
                    b[i] = *(const bf16x8*)&img[buf][bch][img_idx(wc * 64 + i * 32 + cg, h * 8 + q * 4)];
                }
                acc[0][0] = __builtin_amdgcn_mfma_f32_32x32x16_bf16(a[0], b[0], acc[0][0], 0, 0, 0);
                acc[0][1] = __builtin_amdgcn_mfma_f32_32x32x16_bf16(a[0], b[1], acc[0][1], 0, 0, 0);
                acc[1][0] = __builtin_amdgcn_mfma_f32_32x32x16_bf16(a[1], b[0], acc[1][0], 0, 0, 0);
                acc[1][1] = __builtin_amdgcn_mfma_f32_32x32x16_bf16(a[1], b[1], acc[1][1], 0, 0, 0);
            }
            __syncthreads();
        }
    }

    // split-K partial out (no atomics)
    float* gp = ws + WS_GPART + (size_t)split * GP_PER_SPLIT
              + ((size_t)tile * C * 2 + cls * 2 + inp) * GP_TILE;
    #pragma unroll
    for (int i = 0; i < 2; ++i)
        #pragma unroll
        for (int j = 0; j < 2; ++j)
            #pragma unroll
            for (int r = 0; r < 16; ++r) {
                const int row = wr * 64 + i * 32 + (r & 3) + 8 * (r >> 2) + 4 * q;
                const int col = wc * 64 + j * 32 + cg;
                gp[row * 128 + col] = acc[i][j][r];
            }

    if (tile == 1) {
        const int c0 = half * 128 + 2 * cp;
        atomicAdd(&sstats[c0],           s1x);
        atomicAdd(&sstats[c0 + 1],       s1y);
        atomicAdd(&sstats[256 + c0],     s2x);
        atomicAdd(&sstats[256 + c0 + 1], s2y);
        __syncthreads();
        const size_t base = (((size_t)split * C + cls) * 2 + inp) * 512;
        ws[WS_PSUM + base + t]       = sstats[t];
        ws[WS_PSUM + base + 256 + t] = sstats[256 + t];
    }
}

// Fold per-split stat partials into class stats.
__global__ __launch_bounds__(256) void k_reduce2(float* __restrict__ ws) {
    const int t = threadIdx.x;
    const int c = blockIdx.x;
    const int stat = blockIdx.y & 1, inp = blockIdx.y >> 1;
    float acc = 0.f;
    #pragma unroll
    for (int sp = 0; sp < NSPLIT; ++sp)
        acc += ws[WS_PSUM + (((size_t)sp * C + c) * 2 + inp) * 512 + stat * 256 + t];
    const int base = stat ? (inp ? WS_SQ_B : WS_SQ_A)
                          : (inp ? WS_SUMS_B : WS_SUMS_A);
    ws[base + c * D + t] = acc;
}

// Sum split partials, form cov, accumulate weighted off-diagonal cov^2.
__global__ __launch_bounds__(256) void k_cov(const int* __restrict__ counts,
                                             float* __restrict__ ws) {
    const int t = threadIdx.x;
    const int tile = blockIdx.x;
    const int tx = tile >> 1, ty = (tile + 1) >> 1;
    const int cls = blockIdx.y, inp = blockIdx.z;
    const int cnt = counts[cls];
    const float fc = (float)cnt;
    const float cinv = 1.f / fc, uinv = 1.f / (fc - 1.f);
    const float wgt = (tx == ty) ? 1.f : 2.f;
    const int cm0 = tx * 128, cn0 = ty * 128;
    __shared__ float M[D];
    const float* sums = ws + (inp ? WS_SUMS_B : WS_SUMS_A) + cls * D;
    M[t] = sums[t] * cinv;
    __syncthreads();

    const float* gp0 = ws + WS_GPART + ((size_t)tile * C * 2 + cls * 2 + inp) * GP_TILE;
    float local = 0.f;
    #pragma unroll 4
    for (int k = 0; k < 64; ++k) {
        const int e = k * 256 + t;
        float g = 0.f;
        #pragma unroll
        for (int s = 0; s < NSPLIT; ++s)
            g += gp0[(size_t)s * GP_PER_SPLIT + e];
        const int row = e >> 7, col = e & 127;
        const int gm = cm0 + row, gn = cn0 + col;
        const float cov = (g - fc * M[gm] * M[gn]) * uinv;
        if (gm != gn) local += wgt * cov * cov;
    }
    for (int o = 32; o > 0; o >>= 1) local += __shfl_down(local, o, 64);
    __shared__ float red[4];
    if ((t & 63) == 0) red[t >> 6] = local;
    __syncthreads();
    if (t == 0) atomicAdd(&ws[WS_COV], red[0] + red[1] + red[2] + red[3]);
}

// ---------------- fallback (tiny ws): round-2 kernels ----------------
__global__ __launch_bounds__(256) void k_stats(const float* __restrict__ za,
                                               const float* __restrict__ zb,
                                               const int* __restrict__ labels,
                                               float* __restrict__ ws) {
    const int t = threadIdx.x;
    __shared__ float S[4][C * D];
    __shared__ int lab[512];
    for (int i = t; i < 4 * C * D; i += 256) ((float*)S)[i] = 0.f;
    const int r0 = blockIdx.x * 512;
    for (int i = t; i < 512; i += 256) lab[i] = labels[r0 + i];
    __syncthreads();
    float invp = 0.f;
    #pragma unroll 4
    for (int rr = 0; rr < 512; ++rr) {
        const int l = lab[rr];
        const float a = za[(size_t)(r0 + rr) * D + t];
        const float b = zb[(size_t)(r0 + rr) * D + t];
        const float dd = a - b;
        invp += dd * dd;
        S[0][l * D + t] += a;
        S[1][l * D + t] += a * a;
        S[2][l * D + t] += b;
        S[3][l * D + t] += b * b;
    }
    __syncthreads();
    #pragma unroll
    for (int c = 0; c < C; ++c) {
        atomicAdd(&ws[WS_SUMS_A + c * D + t], S[0][c * D + t]);
        atomicAdd(&ws[WS_SQ_A   + c * D + t], S[1][c * D + t]);
        atomicAdd(&ws[WS_SUMS_B + c * D + t], S[2][c * D + t]);
        atomicAdd(&ws[WS_SQ_B   + c * D + t], S[3][c * D + t]);
    }
    for (int o = 32; o > 0; o >>= 1) invp += __shfl_down(invp, o, 64);
    if ((t & 63) == 0) atomicAdd(&ws[WS_INV], invp);
}

#define STR 20
#define KB 32
__global__ __launch_bounds__(256) void k_gram_slow(const float* __restrict__ za,
                                                   const float* __restrict__ zb,
                                                   const int* __restrict__ perm,
                                                   const int* __restrict__ counts,
                                                   float* __restrict__ ws) {
    const int t = threadIdx.x;
    const int tile = blockIdx.x;
    const int tx = tile >> 1, ty = (tile + 1) >> 1;
    const int cls = blockIdx.y;
    const int inp = blockIdx.z;
    const float* X = inp ? zb : za;
    const float* sums = ws + (inp ? WS_SUMS_B : WS_SUMS_A) + cls * D;
    int offs = 0;
    for (int c = 0; c < cls; ++c) offs += counts[c];
    const int cnt = counts[cls];
    const int cm0 = tx * 128, cn0 = ty * 128;
    __shared__ __align__(16) unsigned lds[2][256 * STR];
    const int p = t >> 5, cq = t & 31;
    const int lane = t & 63, w = t >> 6;
    const int wr = w & 1, wc = w >> 1;
    const int cg = lane & 31, q = lane >> 5;
    f32x16 acc[2][2];
    #pragma unroll
    for (int i = 0; i < 2; ++i)
        #pragma unroll
        for (int j = 0; j < 2; ++j) acc[i][j] = 0.0f;
    const int nsteps = (cnt + KB - 1) / KB;
    auto stage = [&](int buf, int k0) {
        #pragma unroll
        for (int ch = 0; ch < 2; ++ch) {
            const int gc = (ch ? cn0 : cm0) + 4 * cq;
            #pragma unroll
            for (int sub = 0; sub < 2; ++sub) {
                const int rr = sub * 16 + 2 * p;
                const int r0 = k0 + rr, r1 = r0 + 1;
                float4 v0 = make_float4(0.f, 0.f, 0.f, 0.f), v1 = v0;
                if (r0 < cnt) v0 = *(const float4*)(X + (size_t)perm[offs + r0] * D + gc);
                if (r1 < cnt) v1 = *(const float4*)(X + (size_t)perm[offs + r1] * D + gc);
                unsigned* dst = &lds[buf][(ch * 128 + 4 * cq) * STR + (rr >> 1)];
                dst[0 * STR] = pack_bf16(v0.x, v1.x);
                dst[1 * STR] = pack_bf16(v0.y, v1.y);
                dst[2 * STR] = pack_bf16(v0.z, v1.z);
                dst[3 * STR] = pack_bf16(v0.w, v1.w);
            }
        }
    };
    auto frag = [&](int buf, int colbase, int h) -> bf16x8 {
        return *(const bf16x8*)&lds[buf][(colbase + cg) * STR + h * 8 + q * 4];
    };
    stage(0, 0);
    for (int s = 0; s < nsteps; ++s) {
        __syncthreads();
        const int buf = s & 1;
        if (s + 1 < nsteps) stage(buf ^ 1, (s + 1) * KB);
        #pragma unroll
        for (int h = 0; h < 2; ++h) {
            bf16x8 a0 = frag(buf, wr * 64, h);
            bf16x8 a1 = frag(buf, wr * 64 + 32, h);
            bf16x8 b0 = frag(buf, 128 + wc * 64, h);
            bf16x8 b1 = frag(buf, 128 + wc * 64 + 32, h);
            acc[0][0] = __builtin_amdgcn_mfma_f32_32x32x16_bf16(a0, b0, acc[0][0], 0, 0, 0);
            acc[0][1] = __builtin_amdgcn_mfma_f32_32x32x16_bf16(a0, b1, acc[0][1], 0, 0, 0);
            acc[1][0] = __builtin_amdgcn_mfma_f32_32x32x16_bf16(a1, b0, acc[1][0], 0, 0, 0);
            acc[1][1] = __builtin_amdgcn_mfma_f32_32x32x16_bf16(a1, b1, acc[1][1], 0, 0, 0);
        }
    }
    const float fc = (float)cnt;
    const float cinv = 1.f / fc, uinv = 1.f / (fc - 1.f);
    const float wgt = (tx == ty) ? 1.f : 2.f;
    float local = 0.f;
    #pragma unroll
    for (int i = 0; i < 2; ++i) {
        #pragma unroll
        for (int j = 0; j < 2; ++j) {
            const int gn = cn0 + wc * 64 + j * 32 + (lane & 31);
            const float mn = sums[gn] * cinv;
            #pragma unroll
            for (int r = 0; r < 16; ++r) {
                const int row = (r & 3) + 8 * (r >> 2) + 4 * q;
                const int gm = cm0 + wr * 64 + i * 32 + row;
                const float cov = (acc[i][j][r] - fc * (sums[gm] * cinv) * mn) * uinv;
                if (gm != gn) local += wgt * cov * cov;
            }
        }
    }
    for (int o = 32; o > 0; o >>= 1) local += __shfl_down(local, o, 64);
    if (lane == 0) atomicAdd(&ws[WS_COV], local);
}

__global__ __launch_bounds__(256) void k_final(const float* __restrict__ ws,
                                               float* __restrict__ out) {
    __shared__ float M[C * D];
    __shared__ float redv[4];
    __shared__ float redp[4];
    const int t = threadIdx.x;
    const int* counts = (const int*)ws + WS_COUNTS;

    float vsum = 0.f;
    for (int idx = t; idx < 2 * C * D; idx += 256) {
        const int inp = idx >> 12;
        const int cd = idx & 4095;
        const int c = cd >> 8;
        const float cnt = (float)counts[c];
        const float s  = ws[(inp ? WS_SUMS_B : WS_SUMS_A) + cd];
        const float sq = ws[(inp ? WS_SQ_B   : WS_SQ_A)   + cd];
        const float mean = s / cnt;
        const float var = (sq - cnt * mean * mean) / (cnt - 1.f);
        vsum += fmaxf(1.f - sqrtf(var + 1e-4f), 0.f);
    }
    for (int cd = t; cd < C * D; cd += 256) {
        const int c = cd >> 8;
        const float cnt = (float)counts[c];
        M[cd] = 0.5f * (ws[WS_SUMS_A + cd] + ws[WS_SUMS_B + cd]) / cnt;
    }
    for (int o = 32; o > 0; o >>= 1) vsum += __shfl_down(vsum, o, 64);
    if ((t & 63) == 0) redv[t >> 6] = vsum;
    __syncthreads();

    const int wv = t >> 6, ln = t & 63;
    float psum = 0.f;
    int p = 0;
    for (int i = 0; i < C; ++i) {
        for (int j = i + 1; j < C; ++j, ++p) {
            if ((p & 3) != wv) continue;
            float d2 = 0.f;
            #pragma unroll
            for (int d = ln; d < D; d += 64) {
                const float df = M[i * D + d] - M[j * D + d];
                d2 += df * df;
            }
            for (int o = 32; o > 0; o >>= 1) d2 += __shfl_down(d2, o, 64);
            if (ln == 0) {
                const float dist = sqrtf(d2);
                const float r = fmaxf(50.f - dist, 0.f);
                psum += r * r;
            }
        }
    }
    if (ln == 0) redp[wv] = psum;
    __syncthreads();

    if (t == 0) {
        const float var_total = redv[0] + redv[1] + redv[2] + redv[3];
        const float var_loss = var_total / 8192.f;
        const float class_sum = redp[0] + redp[1] + redp[2] + redp[3];
        const float class_loss = class_sum / 120.f;
        const float inv_loss = ws[WS_INV] / (float)(N_ROWS * D);
        const float cov_loss = 0.5f * ws[WS_COV] / (float)(C * D);
        out[0] = 25.f * inv_loss + 25.f * var_loss + 1.f * cov_loss + 50.f * class_loss;
    }
}

extern "C" void kernel_launch(void* const* d_in, const int* in_sizes, int n_in,
                              void* d_out, int out_size, void* d_ws, size_t ws_size,
                              hipStream_t stream) {
    const float* za = (const float*)d_in[0];
    const float* zb = (const float*)d_in[1];
    const int* labels = (const int*)d_in[2];
    float* out = (float*)d_out;
    float* ws = (float*)d_ws;
    int* wsi = (int*)d_ws;

    hipMemsetAsync(d_ws, 0, WS_ZERO_FLOATS * sizeof(float), stream);
    k_hist<<<128, 256, 0, stream>>>(labels, wsi + WS_COUNTS);
    k_scan<<<1, 64, 0, stream>>>(wsi + WS_COUNTS, wsi + WS_CURSOR,
                                 wsi + WS_POFFP, wsi + WS_EOFF);
    k_scatter<<<128, 256, 0, stream>>>(labels, wsi + WS_CURSOR, wsi + WS_PERM);

    if (ws_size >= NEED_A) {
        k_inv<<<2048, 256, 0, stream>>>(za, zb, ws);
        k_gram3<<<dim3(3 * NSPLIT, C, 2), 256, 0, stream>>>(
            za, zb, wsi + WS_PERM, wsi + WS_COUNTS, wsi + WS_POFFP,
            wsi + WS_EOFF, ws);
        k_reduce2<<<dim3(C, 4), 256, 0, stream>>>(ws);
        k_cov<<<dim3(3, C, 2), 256, 0, stream>>>(wsi + WS_COUNTS, ws);
    } else {
        k_stats<<<64, 256, 0, stream>>>(za, zb, labels, ws);
        k_gram_slow<<<dim3(3, C, 2), 256, 0, stream>>>(za, zb, wsi + WS_PERM,
                                                       wsi + WS_COUNTS, ws);
    }
    k_final<<<1, 256, 0, stream>>>(ws, out);
}

// Round 8
// 194.769 us; speedup vs baseline: 2.2108x; 1.7330x over previous
//
#include <hip/hip_runtime.h>
#include <math.h>

#define N_ROWS 32768
#define D 256
#define C 16

// workspace layout in floats
#define WS_SUMS_A 0
#define WS_SQ_A   4096
#define WS_SUMS_B 8192
#define WS_SQ_B   12288
#define WS_INV    16384
#define WS_COV    16385
#define WS_COUNTS 16392   /* int[16] */
#define WS_CURSOR 16408   /* int[16] */
#define WS_POFFP  16424   /* int[17] 32-row substep offsets */
#define WS_EOFF   16448   /* int[17] row prefix */
#define WS_INVP   16512   /* float[512] per-block inv partials */
#define WS_COVP   17024   /* float[96] per-block cov partials */
#define WS_PERM   17152   /* int[32768] */
#define WS_ZERO_FLOATS 16408

#define WS_PSUM   49920   /* [8 split][16 cls][2 inp][2 stat][256] */
#define WS_GPART  180992
#define GP_TILE   16384
#define GP_PER_SPLIT (3 * C * 2 * GP_TILE)   /* 1,572,864 floats */
#define NSPLIT    8
#define RIDX_CAP  1024
#define NEED_A ((size_t)(WS_GPART + NSPLIT * GP_PER_SPLIT) * 4)   /* ~48.7 MiB */

typedef __attribute__((ext_vector_type(8))) __bf16 bf16x8;
typedef __attribute__((ext_vector_type(16))) float f32x16;

__device__ inline unsigned bf16_rne(float f) {
    unsigned u = __float_as_uint(f);
    return (u + 0x7fffu + ((u >> 16) & 1u)) >> 16;
}
__device__ inline unsigned pack_bf16(float lo, float hi) {
    return bf16_rne(lo) | (bf16_rne(hi) << 16);
}
// Conflict-tame MFMA image: stride 17 (odd -> full 32-bank coverage),
// k-rotation spreads write quads; 4-dword groups stay contiguous (b128 reads).
__device__ inline int img_idx(int c, int s) {
    return c * 17 + ((s + ((c >> 3) & 12)) & 15);
}

__global__ __launch_bounds__(512) void k_hist(const int* __restrict__ labels,
                                              int* __restrict__ counts) {
    __shared__ int h[C];
    const int t = threadIdx.x;
    if (t < C) h[t] = 0;
    __syncthreads();
    const int i = blockIdx.x * 512 + t;
    atomicAdd(&h[labels[i]], 1);
    __syncthreads();
    if (t < C) atomicAdd(&counts[t], h[t]);
}

__global__ void k_scan(const int* __restrict__ counts, int* __restrict__ cursor,
                       int* __restrict__ poffp, int* __restrict__ eoffp) {
    if (threadIdx.x == 0) {
        int off = 0, po = 0;
        for (int c = 0; c < C; ++c) {
            cursor[c] = off;
            eoffp[c] = off;
            poffp[c] = po;
            off += counts[c];
            po += (counts[c] + 31) >> 5;
        }
        poffp[C] = po;
        eoffp[C] = off;
    }
}

__global__ __launch_bounds__(512) void k_scatter(const int* __restrict__ labels,
                                                 int* __restrict__ cursor,
                                                 int* __restrict__ perm) {
    __shared__ int lh[C];
    __shared__ int lbase[C];
    const int t = threadIdx.x;
    if (t < C) lh[t] = 0;
    __syncthreads();
    const int i = blockIdx.x * 512 + t;
    const int lab = labels[i];
    const int lr = atomicAdd(&lh[lab], 1);
    __syncthreads();
    if (t < C) lbase[t] = atomicAdd(&cursor[t], lh[t]);
    __syncthreads();
    perm[lbase[lab] + lr] = i;
}

// Streaming inv_loss: per-block partial -> STORE to distinct slot (no
// same-address atomic convoy — that convoy was R7's 116us k_inv).
__global__ __launch_bounds__(256) void k_inv(const float* __restrict__ za,
                                             const float* __restrict__ zb,
                                             float* __restrict__ ws) {
    const int t = threadIdx.x;
    const int base = blockIdx.x * 4096 + t;
    float acc = 0.f;
    #pragma unroll
    for (int k = 0; k < 16; ++k) {
        const int i = base + k * 256;
        const float4 a = ((const float4*)za)[i];
        const float4 b = ((const float4*)zb)[i];
        const float dx = a.x - b.x, dy = a.y - b.y;
        const float dz = a.z - b.z, dw = a.w - b.w;
        acc += dx * dx + dy * dy + dz * dz + dw * dw;
    }
    for (int o = 32; o > 0; o >>= 1) acc += __shfl_down(acc, o, 64);
    __shared__ float red[4];
    if ((t & 63) == 0) red[t >> 6] = acc;
    __syncthreads();
    if (t == 0) ws[WS_INVP + blockIdx.x] = red[0] + red[1] + red[2] + red[3];
}

// Fused gather + bf16 pack + split-K MFMA Gram (+ class stats on tile 1).
// ridx preloaded to LDS (no dependent perm->X chain); float4 row loads held in
// registers across the MFMA phase (explicit load/compute overlap); single
// 17.4KB image buffer, two barriers/substep; no global atomics.
__global__ __launch_bounds__(256) void k_gram4(const float* __restrict__ za,
                                               const float* __restrict__ zb,
                                               const int* __restrict__ perm,
                                               const int* __restrict__ counts,
                                               const int* __restrict__ poffp,
                                               const int* __restrict__ eoffp,
                                               float* __restrict__ ws) {
    const int t = threadIdx.x;
    const int tile = blockIdx.x >> 3;        // 0:(0,0) 1:(0,1) 2:(1,1)
    const int split = blockIdx.x & 7;
    const int tx = tile >> 1, ty = (tile + 1) >> 1;
    const int cls = blockIdx.y, inp = blockIdx.z;
    const float* X = inp ? zb : za;
    const int cnt = counts[cls];
    const int eoff = eoffp[cls];
    const int nsteps = poffp[cls + 1] - poffp[cls];
    const int chunk = (nsteps + NSPLIT - 1) / NSPLIT;
    const int sb = split * chunk;
    const int se = min(sb + chunk, nsteps);
    const bool diag = (tx == ty);
    const int cm0 = tx * 128, cn0 = ty * 128;

    __shared__ __align__(16) unsigned img[2][2176];   // 17.4 KB
    __shared__ float sstats[512];                     // 2 KB
    __shared__ int ridx[RIDX_CAP];                    // 4 KB

    for (int i = t; i < 512; i += 256) sstats[i] = 0.f;
    const int nl = (se > sb) ? (se - sb) * 32 : 0;
    for (int i = t; i < min(nl, RIDX_CAP); i += 256) {
        const int gr = sb * 32 + i;
        ridx[i] = (gr < cnt) ? perm[eoff + gr] : -1;
    }
    __syncthreads();

    auto rowidx = [&](int li) -> int {
        if (li < RIDX_CAP) return ridx[li];
        const int gr = sb * 32 + li;
        return (gr < cnt) ? perm[eoff + gr] : -1;
    };

    const int lane = t & 63, w = t >> 6;
    const int wr = w & 1, wc = w >> 1;
    const int cg = lane & 31, q = lane >> 5;

    // staging ownership
    int img_sel, lc, kp0, nIt;
    if (diag) {
        img_sel = 0; lc = 4 * (t & 31); kp0 = (t >> 5) * 2; nIt = 2;
    } else {
        const int half = t >> 7, u = t & 127;
        img_sel = half; lc = 4 * (u & 31); kp0 = (u >> 5) * 4; nIt = 4;
    }
    const int gcol = (diag ? cm0 : (img_sel ? cn0 : cm0)) + lc;

    f32x16 acc[2][2];
    #pragma unroll
    for (int i = 0; i < 2; ++i)
        #pragma unroll
        for (int j = 0; j < 2; ++j) acc[i][j] = 0.0f;

    float s1r[4] = {0.f, 0.f, 0.f, 0.f};
    float s2r[4] = {0.f, 0.f, 0.f, 0.f};
    float4 f0[4], f1[4];

    auto load_regs = [&](int s) {
        #pragma unroll
        for (int it = 0; it < 4; ++it) if (it < nIt) {
            const int li = (s - sb) * 32 + 2 * (kp0 + it);
            const int r0 = rowidx(li), r1 = rowidx(li + 1);
            f0[it] = (r0 >= 0) ? *(const float4*)(X + (size_t)r0 * D + gcol)
                               : make_float4(0.f, 0.f, 0.f, 0.f);
            f1[it] = (r1 >= 0) ? *(const float4*)(X + (size_t)r1 * D + gcol)
                               : make_float4(0.f, 0.f, 0.f, 0.f);
        }
    };
    auto pack_store = [&]() {
        #pragma unroll
        for (int it = 0; it < 4; ++it) if (it < nIt) {
            const int kp = kp0 + it;
            img[img_sel][img_idx(lc + 0, kp)] = pack_bf16(f0[it].x, f1[it].x);
            img[img_sel][img_idx(lc + 1, kp)] = pack_bf16(f0[it].y, f1[it].y);
            img[img_sel][img_idx(lc + 2, kp)] = pack_bf16(f0[it].z, f1[it].z);
            img[img_sel][img_idx(lc + 3, kp)] = pack_bf16(f0[it].w, f1[it].w);
            if (tile == 1) {
                s1r[0] += f0[it].x + f1[it].x; s2r[0] += f0[it].x * f0[it].x + f1[it].x * f1[it].x;
                s1r[1] += f0[it].y + f1[it].y; s2r[1] += f0[it].y * f0[it].y + f1[it].y * f1[it].y;
                s1r[2] += f0[it].z + f1[it].z; s2r[2] += f0[it].z * f0[it].z + f1[it].z * f1[it].z;
                s1r[3] += f0[it].w + f1[it].w; s2r[3] += f0[it].w * f0[it].w + f1[it].w * f1[it].w;
            }
        }
    };

    const int bch = diag ? 0 : 1;
    if (sb < se) {
        load_regs(sb);
        pack_store();
        __syncthreads();
        for (int s = sb; s < se; ++s) {
            const bool more = (s + 1 < se);
            if (more) load_regs(s + 1);      // in flight across MFMAs
            #pragma unroll
            for (int h = 0; h < 2; ++h) {
                bf16x8 a[2], b[2];
                #pragma unroll
                for (int i = 0; i < 2; ++i) {
                    a[i] = *(const bf16x8*)&img[0][img_idx(wr * 64 + i * 32 + cg, h * 8 + q * 4)];
                    b[i] = *(const bf16x8*)&img[bch][img_idx(wc * 64 + i * 32 + cg, h * 8 + q * 4)];
                }
                acc[0][0] = __builtin_amdgcn_mfma_f32_32x32x16_bf16(a[0], b[0], acc[0][0], 0, 0, 0);
                acc[0][1] = __builtin_amdgcn_mfma_f32_32x32x16_bf16(a[0], b[1], acc[0][1], 0, 0, 0);
                acc[1][0] = __builtin_amdgcn_mfma_f32_32x32x16_bf16(a[1], b[0], acc[1][0], 0, 0, 0);
                acc[1][1] = __builtin_amdgcn_mfma_f32_32x32x16_bf16(a[1], b[1], acc[1][1], 0, 0, 0);
            }
            __syncthreads();                 // all frag reads of img done
            if (more) {
                pack_store();
                __syncthreads();             // img ready for next MFMA
            }
        }
    }

    // split-K partial out (plain stores)
    float* gp = ws + WS_GPART + (size_t)split * GP_PER_SPLIT
              + ((size_t)tile * C * 2 + cls * 2 + inp) * GP_TILE;
    #pragma unroll
    for (int i = 0; i < 2; ++i)
        #pragma unroll
        for (int j = 0; j < 2; ++j)
            #pragma unroll
            for (int r = 0; r < 16; ++r) {
                const int row = wr * 64 + i * 32 + (r & 3) + 8 * (r >> 2) + 4 * q;
                const int col = wc * 64 + j * 32 + cg;
                gp[row * 128 + col] = acc[i][j][r];
            }

    if (tile == 1) {
        const int c0 = img_sel * 128 + lc;
        #pragma unroll
        for (int d = 0; d < 4; ++d) {
            atomicAdd(&sstats[c0 + d],       s1r[d]);
            atomicAdd(&sstats[256 + c0 + d], s2r[d]);
        }
        __syncthreads();
        const size_t base = (((size_t)split * C + cls) * 2 + inp) * 512;
        ws[WS_PSUM + base + t]       = sstats[t];
        ws[WS_PSUM + base + 256 + t] = sstats[256 + t];
    }
}

// Fold per-split stat partials into class stats.
__global__ __launch_bounds__(256) void k_reduce2(float* __restrict__ ws) {
    const int t = threadIdx.x;
    const int c = blockIdx.x;
    const int stat = blockIdx.y & 1, inp = blockIdx.y >> 1;
    float acc = 0.f;
    #pragma unroll
    for (int sp = 0; sp < NSPLIT; ++sp)
        acc += ws[WS_PSUM + (((size_t)sp * C + c) * 2 + inp) * 512 + stat * 256 + t];
    const int base = stat ? (inp ? WS_SQ_B : WS_SQ_A)
                          : (inp ? WS_SUMS_B : WS_SUMS_A);
    ws[base + c * D + t] = acc;
}

// Sum split partials, form cov, per-block cov^2 partial -> STORE (no atomic).
__global__ __launch_bounds__(256) void k_cov(const int* __restrict__ counts,
                                             float* __restrict__ ws) {
    const int t = threadIdx.x;
    const int tile = blockIdx.x;
    const int tx = tile >> 1, ty = (tile + 1) >> 1;
    const int cls = blockIdx.y, inp = blockIdx.z;
    const int cnt = counts[cls];
    const float fc = (float)cnt;
    const float cinv = 1.f / fc, uinv = 1.f / (fc - 1.f);
    const float wgt = (tx == ty) ? 1.f : 2.f;
    const int cm0 = tx * 128, cn0 = ty * 128;
    __shared__ float M[D];
    const float* sums = ws + (inp ? WS_SUMS_B : WS_SUMS_A) + cls * D;
    M[t] = sums[t] * cinv;
    __syncthreads();

    const float* gp0 = ws + WS_GPART + ((size_t)tile * C * 2 + cls * 2 + inp) * GP_TILE;
    float local = 0.f;
    #pragma unroll 4
    for (int k = 0; k < 64; ++k) {
        const int e = k * 256 + t;
        float g = 0.f;
        #pragma unroll
        for (int s = 0; s < NSPLIT; ++s)
            g += gp0[(size_t)s * GP_PER_SPLIT + e];
        const int row = e >> 7, col = e & 127;
        const int gm = cm0 + row, gn = cn0 + col;
        const float cov = (g - fc * M[gm] * M[gn]) * uinv;
        if (gm != gn) local += wgt * cov * cov;
    }
    for (int o = 32; o > 0; o >>= 1) local += __shfl_down(local, o, 64);
    __shared__ float red[4];
    if ((t & 63) == 0) red[t >> 6] = local;
    __syncthreads();
    if (t == 0)
        ws[WS_COVP + blockIdx.x + 3 * blockIdx.y + 3 * C * blockIdx.z] =
            red[0] + red[1] + red[2] + red[3];
}

// ---------------- fallback (tiny ws): round-2 kernels ----------------
__global__ __launch_bounds__(256) void k_stats(const float* __restrict__ za,
                                               const float* __restrict__ zb,
                                               const int* __restrict__ labels,
                                               float* __restrict__ ws) {
    const int t = threadIdx.x;
    __shared__ float S[4][C * D];
    __shared__ int lab[512];
    for (int i = t; i < 4 * C * D; i += 256) ((float*)S)[i] = 0.f;
    const int r0 = blockIdx.x * 512;
    for (int i = t; i < 512; i += 256) lab[i] = labels[r0 + i];
    __syncthreads();
    float invp = 0.f;
    #pragma unroll 4
    for (int rr = 0; rr < 512; ++rr) {
        const int l = lab[rr];
        const float a = za[(size_t)(r0 + rr) * D + t];
        const float b = zb[(size_t)(r0 + rr) * D + t];
        const float dd = a - b;
        invp += dd * dd;
        S[0][l * D + t] += a;
        S[1][l * D + t] += a * a;
        S[2][l * D + t] += b;
        S[3][l * D + t] += b * b;
    }
    __syncthreads();
    #pragma unroll
    for (int c = 0; c < C; ++c) {
        atomicAdd(&ws[WS_SUMS_A + c * D + t], S[0][c * D + t]);
        atomicAdd(&ws[WS_SQ_A   + c * D + t], S[1][c * D + t]);
        atomicAdd(&ws[WS_SUMS_B + c * D + t], S[2][c * D + t]);
        atomicAdd(&ws[WS_SQ_B   + c * D + t], S[3][c * D + t]);
    }
    for (int o = 32; o > 0; o >>= 1) invp += __shfl_down(invp, o, 64);
    if ((t & 63) == 0) atomicAdd(&ws[WS_INV], invp);
}

#define STR 20
#define KB 32
__global__ __launch_bounds__(256) void k_gram_slow(const float* __restrict__ za,
                                                   const float* __restrict__ zb,
                                                   const int* __restrict__ perm,
                                                   const int* __restrict__ counts,
                                                   float* __restrict__ ws) {
    const int t = threadIdx.x;
    const int tile = blockIdx.x;
    const int tx = tile >> 1, ty = (tile + 1) >> 1;
    const int cls = blockIdx.y;
    const int inp = blockIdx.z;
    const float* X = inp ? zb : za;
    const float* sums = ws + (inp ? WS_SUMS_B : WS_SUMS_A) + cls * D;
    int offs = 0;
    for (int c = 0; c < cls; ++c) offs += counts[c];
    const int cnt = counts[cls];
    const int cm0 = tx * 128, cn0 = ty * 128;
    __shared__ __align__(16) unsigned lds[2][256 * STR];
    const int p = t >> 5, cq = t & 31;
    const int lane = t & 63, w = t >> 6;
    const int wr = w & 1, wc = w >> 1;
    const int cg = lane & 31, q = lane >> 5;
    f32x16 acc[2][2];
    #pragma unroll
    for (int i = 0; i < 2; ++i)
        #pragma unroll
        for (int j = 0; j < 2; ++j) acc[i][j] = 0.0f;
    const int nsteps = (cnt + KB - 1) / KB;
    auto stage = [&](int buf, int k0) {
        #pragma unroll
        for (int ch = 0; ch < 2; ++ch) {
            const int gc = (ch ? cn0 : cm0) + 4 * cq;
            #pragma unroll
            for (int sub = 0; sub < 2; ++sub) {
                const int rr = sub * 16 + 2 * p;
                const int r0 = k0 + rr, r1 = r0 + 1;
                float4 v0 = make_float4(0.f, 0.f, 0.f, 0.f), v1 = v0;
                if (r0 < cnt) v0 = *(const float4*)(X + (size_t)perm[offs + r0] * D + gc);
                if (r1 < cnt) v1 = *(const float4*)(X + (size_t)perm[offs + r1] * D + gc);
                unsigned* dst = &lds[buf][(ch * 128 + 4 * cq) * STR + (rr >> 1)];
                dst[0 * STR] = pack_bf16(v0.x, v1.x);
                dst[1 * STR] = pack_bf16(v0.y, v1.y);
                dst[2 * STR] = pack_bf16(v0.z, v1.z);
                dst[3 * STR] = pack_bf16(v0.w, v1.w);
            }
        }
    };
    auto frag = [&](int buf, int colbase, int h) -> bf16x8 {
        return *(const bf16x8*)&lds[buf][(colbase + cg) * STR + h * 8 + q * 4];
    };
    stage(0, 0);
    for (int s = 0; s < nsteps; ++s) {
        __syncthreads();
        const int buf = s & 1;
        if (s + 1 < nsteps) stage(buf ^ 1, (s + 1) * KB);
        #pragma unroll
        for (int h = 0; h < 2; ++h) {
            bf16x8 a0 = frag(buf, wr * 64, h);
            bf16x8 a1 = frag(buf, wr * 64 + 32, h);
            bf16x8 b0 = frag(buf, 128 + wc * 64, h);
            bf16x8 b1 = frag(buf, 128 + wc * 64 + 32, h);
            acc[0][0] = __builtin_amdgcn_mfma_f32_32x32x16_bf16(a0, b0, acc[0][0], 0, 0, 0);
            acc[0][1] = __builtin_amdgcn_mfma_f32_32x32x16_bf16(a0, b1, acc[0][1], 0, 0, 0);
            acc[1][0] = __builtin_amdgcn_mfma_f32_32x32x16_bf16(a1, b0, acc[1][0], 0, 0, 0);
            acc[1][1] = __builtin_amdgcn_mfma_f32_32x32x16_bf16(a1, b1, acc[1][1], 0, 0, 0);
        }
    }
    const float fc = (float)cnt;
    const float cinv = 1.f / fc, uinv = 1.f / (fc - 1.f);
    const float wgt = (tx == ty) ? 1.f : 2.f;
    float local = 0.f;
    #pragma unroll
    for (int i = 0; i < 2; ++i) {
        #pragma unroll
        for (int j = 0; j < 2; ++j) {
            const int gn = cn0 + wc * 64 + j * 32 + (lane & 31);
            const float mn = sums[gn] * cinv;
            #pragma unroll
            for (int r = 0; r < 16; ++r) {
                const int row = (r & 3) + 8 * (r >> 2) + 4 * q;
                const int gm = cm0 + wr * 64 + i * 32 + row;
                const float cov = (acc[i][j][r] - fc * (sums[gm] * cinv) * mn) * uinv;
                if (gm != gn) local += wgt * cov * cov;
            }
        }
    }
    for (int o = 32; o > 0; o >>= 1) local += __shfl_down(local, o, 64);
    if (lane == 0) atomicAdd(&ws[WS_COV], local);
}

__global__ __launch_bounds__(256) void k_final(const float* __restrict__ ws,
                                               float* __restrict__ out,
                                               int fast) {
    __shared__ float M[C * D];
    __shared__ float redv[4], redi[4], redc[4], redp[4];
    const int t = threadIdx.x;
    const int* counts = (const int*)ws + WS_COUNTS;

    float vsum = 0.f;
    for (int idx = t; idx < 2 * C * D; idx += 256) {
        const int inp = idx >> 12;
        const int cd = idx & 4095;
        const int c = cd >> 8;
        const float cnt = (float)counts[c];
        const float s  = ws[(inp ? WS_SUMS_B : WS_SUMS_A) + cd];
        const float sq = ws[(inp ? WS_SQ_B   : WS_SQ_A)   + cd];
        const float mean = s / cnt;
        const float var = (sq - cnt * mean * mean) / (cnt - 1.f);
        vsum += fmaxf(1.f - sqrtf(var + 1e-4f), 0.f);
    }
    float isum, csum;
    if (fast) {
        isum = ws[WS_INVP + t] + ws[WS_INVP + 256 + t];
        csum = (t < 96) ? ws[WS_COVP + t] : 0.f;
    } else {
        isum = (t == 0) ? ws[WS_INV] : 0.f;
        csum = (t == 0) ? ws[WS_COV] : 0.f;
    }
    for (int cd = t; cd < C * D; cd += 256) {
        const int c = cd >> 8;
        const float cnt = (float)counts[c];
        M[cd] = 0.5f * (ws[WS_SUMS_A + cd] + ws[WS_SUMS_B + cd]) / cnt;
    }
    for (int o = 32; o > 0; o >>= 1) {
        vsum += __shfl_down(vsum, o, 64);
        isum += __shfl_down(isum, o, 64);
        csum += __shfl_down(csum, o, 64);
    }
    if ((t & 63) == 0) {
        redv[t >> 6] = vsum; redi[t >> 6] = isum; redc[t >> 6] = csum;
    }
    __syncthreads();

    const int wv = t >> 6, ln = t & 63;
    float psum = 0.f;
    int p = 0;
    for (int i = 0; i < C; ++i) {
        for (int j = i + 1; j < C; ++j, ++p) {
            if ((p & 3) != wv) continue;
            float d2 = 0.f;
            #pragma unroll
            for (int d = ln; d < D; d += 64) {
                const float df = M[i * D + d] - M[j * D + d];
                d2 += df * df;
            }
            for (int o = 32; o > 0; o >>= 1) d2 += __shfl_down(d2, o, 64);
            if (ln == 0) {
                const float dist = sqrtf(d2);
                const float r = fmaxf(50.f - dist, 0.f);
                psum += r * r;
            }
        }
    }
    if (ln == 0) redp[wv] = psum;
    __syncthreads();

    if (t == 0) {
        const float var_loss = (redv[0] + redv[1] + redv[2] + redv[3]) / 8192.f;
        const float class_loss = (redp[0] + redp[1] + redp[2] + redp[3]) / 120.f;
        const float inv_loss = (redi[0] + redi[1] + redi[2] + redi[3]) / (float)(N_ROWS * D);
        const float cov_loss = 0.5f * (redc[0] + redc[1] + redc[2] + redc[3]) / (float)(C * D);
        out[0] = 25.f * inv_loss + 25.f * var_loss + 1.f * cov_loss + 50.f * class_loss;
    }
}

extern "C" void kernel_launch(void* const* d_in, const int* in_sizes, int n_in,
                              void* d_out, int out_size, void* d_ws, size_t ws_size,
                              hipStream_t stream) {
    const float* za = (const float*)d_in[0];
    const float* zb = (const float*)d_in[1];
    const int* labels = (const int*)d_in[2];
    float* out = (float*)d_out;
    float* ws = (float*)d_ws;
    int* wsi = (int*)d_ws;

    hipMemsetAsync(d_ws, 0, WS_ZERO_FLOATS * sizeof(float), stream);
    k_hist<<<64, 512, 0, stream>>>(labels, wsi + WS_COUNTS);
    k_scan<<<1, 64, 0, stream>>>(wsi + WS_COUNTS, wsi + WS_CURSOR,
                                 wsi + WS_POFFP, wsi + WS_EOFF);
    k_scatter<<<64, 512, 0, stream>>>(labels, wsi + WS_CURSOR, wsi + WS_PERM);

    if (ws_size >= NEED_A) {
        k_inv<<<512, 256, 0, stream>>>(za, zb, ws);
        k_gram4<<<dim3(3 * NSPLIT, C, 2), 256, 0, stream>>>(
            za, zb, wsi + WS_PERM, wsi + WS_COUNTS, wsi + WS_POFFP,
            wsi + WS_EOFF, ws);
        k_reduce2<<<dim3(C, 4), 256, 0, stream>>>(ws);
        k_cov<<<dim3(3, C, 2), 256, 0, stream>>>(wsi + WS_COUNTS, ws);
        k_final<<<1, 256, 0, stream>>>(ws, out, 1);
    } else {
        k_stats<<<64, 256, 0, stream>>>(za, zb, labels, ws);
        k_gram_slow<<<dim3(3, C, 2), 256, 0, stream>>>(za, zb, wsi + WS_PERM,
                                                       wsi + WS_COUNTS, ws);
        k_final<<<1, 256, 0, stream>>>(ws, out, 0);
    }
}

// Round 9
// 174.267 us; speedup vs baseline: 2.4709x; 1.1176x over previous
//
#include <hip/hip_runtime.h>
#include <math.h>

#define N_ROWS 32768
#define D 256
#define C 16

// workspace layout in floats
#define WS_SUMS_A 0
#define WS_SQ_A   4096
#define WS_SUMS_B 8192
#define WS_SQ_B   12288
#define WS_INV    16384
#define WS_COV    16385
#define WS_COUNTS 16392   /* int[16] */
#define WS_CURSOR 16408   /* int[16] */
#define WS_POFFP  16424   /* int[17] 32-row substep offsets */
#define WS_EOFF   16448   /* int[17] row prefix */
#define WS_INVP   16512   /* float[512] per-block inv partials */
#define WS_COVP   17024   /* float[768] per-block cov partials */
#define WS_PERM   17920   /* int[32768] */
#define WS_ZERO_FLOATS 16408

#define WS_PSUM   50688   /* [8 split][16 cls][2 inp][2 stat][256] */
#define WS_GPART  181760
#define GP_TILE   16384
#define GP_PER_SPLIT (3 * C * 2 * GP_TILE)   /* 1,572,864 floats */
#define NSPLIT    8
#define KC        8       /* k_cov k-split */
#define RIDX_CAP  1024
#define NEED_A ((size_t)(WS_GPART + NSPLIT * GP_PER_SPLIT) * 4)   /* ~51 MiB */

typedef __attribute__((ext_vector_type(8))) __bf16 bf16x8;
typedef __attribute__((ext_vector_type(16))) float f32x16;

__device__ inline unsigned bf16_rne(float f) {
    unsigned u = __float_as_uint(f);
    return (u + 0x7fffu + ((u >> 16) & 1u)) >> 16;
}
__device__ inline unsigned pack_bf16(float lo, float hi) {
    return bf16_rne(lo) | (bf16_rne(hi) << 16);
}
// Image: col-major, stride 20 dwords (16B-aligned -> real ds_*_b128),
// k-rotation rot(c)=(c>>1)&12 permutes 4-dword k-blocks per column: breaks
// stride-20's period-8 bank cycle to <=4-way; transparent because write and
// read apply the same rotation. &12 masking keeps alignment provable.
__device__ inline int img_base4(int c, int kd) {   // kd multiple of 4
    return c * 20 + ((kd + ((c >> 1) & 12)) & 12);
}
__device__ inline int img_base2(int c, int kd) {   // kd even (diag b64 path)
    return c * 20 + ((kd + ((c >> 1) & 12)) & 14);
}

__global__ __launch_bounds__(512) void k_hist(const int* __restrict__ labels,
                                              int* __restrict__ counts) {
    __shared__ int h[C];
    const int t = threadIdx.x;
    if (t < C) h[t] = 0;
    __syncthreads();
    const int i = blockIdx.x * 512 + t;
    atomicAdd(&h[labels[i]], 1);
    __syncthreads();
    if (t < C) atomicAdd(&counts[t], h[t]);
}

__global__ void k_scan(const int* __restrict__ counts, int* __restrict__ cursor,
                       int* __restrict__ poffp, int* __restrict__ eoffp) {
    if (threadIdx.x == 0) {
        int off = 0, po = 0;
        for (int c = 0; c < C; ++c) {
            cursor[c] = off;
            eoffp[c] = off;
            poffp[c] = po;
            off += counts[c];
            po += (counts[c] + 31) >> 5;
        }
        poffp[C] = po;
        eoffp[C] = off;
    }
}

__global__ __launch_bounds__(512) void k_scatter(const int* __restrict__ labels,
                                                 int* __restrict__ cursor,
                                                 int* __restrict__ perm) {
    __shared__ int lh[C];
    __shared__ int lbase[C];
    const int t = threadIdx.x;
    if (t < C) lh[t] = 0;
    __syncthreads();
    const int i = blockIdx.x * 512 + t;
    const int lab = labels[i];
    const int lr = atomicAdd(&lh[lab], 1);
    __syncthreads();
    if (t < C) lbase[t] = atomicAdd(&cursor[t], lh[t]);
    __syncthreads();
    perm[lbase[lab] + lr] = i;
}

// Streaming inv_loss: per-block partial -> distinct slot (no atomic convoy).
__global__ __launch_bounds__(256) void k_inv(const float* __restrict__ za,
                                             const float* __restrict__ zb,
                                             float* __restrict__ ws) {
    const int t = threadIdx.x;
    const int base = blockIdx.x * 4096 + t;
    float acc = 0.f;
    #pragma unroll
    for (int k = 0; k < 16; ++k) {
        const int i = base + k * 256;
        const float4 a = ((const float4*)za)[i];
        const float4 b = ((const float4*)zb)[i];
        const float dx = a.x - b.x, dy = a.y - b.y;
        const float dz = a.z - b.z, dw = a.w - b.w;
        acc += dx * dx + dy * dy + dz * dz + dw * dw;
    }
    for (int o = 32; o > 0; o >>= 1) acc += __shfl_down(acc, o, 64);
    __shared__ float red[4];
    if ((t & 63) == 0) red[t >> 6] = acc;
    __syncthreads();
    if (t == 0) ws[WS_INVP + blockIdx.x] = red[0] + red[1] + red[2] + red[3];
}

// Fused gather + bf16 pack + split-K MFMA Gram (+ class stats on tile 1).
// Double-buffered aligned image: ONE barrier per substep; b128 LDS writes
// (4/thread) and b128 frag reads (8/thread); loads prefetched across MFMAs.
__global__ __launch_bounds__(256) void k_gram5(const float* __restrict__ za,
                                               const float* __restrict__ zb,
                                               const int* __restrict__ perm,
                                               const int* __restrict__ counts,
                                               const int* __restrict__ poffp,
                                               const int* __restrict__ eoffp,
                                               float* __restrict__ ws) {
    const int t = threadIdx.x;
    const int tile = blockIdx.x >> 3;        // 0:(0,0) 1:(0,1) 2:(1,1)
    const int split = blockIdx.x & 7;
    const int tx = tile >> 1, ty = (tile + 1) >> 1;
    const int cls = blockIdx.y, inp = blockIdx.z;
    const float* X = inp ? zb : za;
    const int cnt = counts[cls];
    const int eoff = eoffp[cls];
    const int nsteps = poffp[cls + 1] - poffp[cls];
    const int chunk = (nsteps + NSPLIT - 1) / NSPLIT;
    const int sb = split * chunk;
    const int se = min(sb + chunk, nsteps);
    const bool diag = (tx == ty);
    const int cm0 = tx * 128, cn0 = ty * 128;

    __shared__ __align__(16) unsigned img[2][2][2560];   // 41 KB
    __shared__ float sstats[512];
    __shared__ int ridx[RIDX_CAP];

    for (int i = t; i < 512; i += 256) sstats[i] = 0.f;
    const int nl = (se > sb) ? (se - sb) * 32 : 0;
    for (int i = t; i < min(nl, RIDX_CAP); i += 256) {
        const int gr = sb * 32 + i;
        ridx[i] = (gr < cnt) ? perm[eoff + gr] : -1;
    }
    __syncthreads();

    auto rowidx = [&](int li) -> int {
        if (li < RIDX_CAP) return ridx[li];
        const int gr = sb * 32 + li;
        return (gr < cnt) ? perm[eoff + gr] : -1;
    };

    const int lane = t & 63, w = t >> 6;
    const int wr = w & 1, wc = w >> 1;
    const int cg = lane & 31, q = lane >> 5;

    // staging ownership
    int img_sel, lc, kp0, nIt;
    if (diag) {
        img_sel = 0; lc = 4 * (t & 31); kp0 = 2 * (t >> 5); nIt = 2;   // b64 path
    } else {
        const int half = t >> 7, u = t & 127;
        img_sel = half; lc = 4 * (u & 31); kp0 = 4 * (u >> 5); nIt = 4; // b128 path
    }
    const int gcol = (diag ? cm0 : (img_sel ? cn0 : cm0)) + lc;

    f32x16 acc[2][2];
    #pragma unroll
    for (int i = 0; i < 2; ++i)
        #pragma unroll
        for (int j = 0; j < 2; ++j) acc[i][j] = 0.0f;

    float s1r[4] = {0.f, 0.f, 0.f, 0.f};
    float s2r[4] = {0.f, 0.f, 0.f, 0.f};
    float4 f0[4], f1[4];

    auto load_regs = [&](int s) {
        #pragma unroll
        for (int it = 0; it < 4; ++it) if (it < nIt) {
            const int li = (s - sb) * 32 + 2 * (kp0 + it);
            const int r0 = rowidx(li), r1 = rowidx(li + 1);
            f0[it] = (r0 >= 0) ? *(const float4*)(X + (size_t)r0 * D + gcol)
                               : make_float4(0.f, 0.f, 0.f, 0.f);
            f1[it] = (r1 >= 0) ? *(const float4*)(X + (size_t)r1 * D + gcol)
                               : make_float4(0.f, 0.f, 0.f, 0.f);
        }
    };
    auto pack_store = [&](int buf) {
        if (!diag) {
            unsigned pwq[4][4];
            #pragma unroll
            for (int it = 0; it < 4; ++it) {
                pwq[0][it] = pack_bf16(f0[it].x, f1[it].x);
                pwq[1][it] = pack_bf16(f0[it].y, f1[it].y);
                pwq[2][it] = pack_bf16(f0[it].z, f1[it].z);
                pwq[3][it] = pack_bf16(f0[it].w, f1[it].w);
            }
            #pragma unroll
            for (int d = 0; d < 4; ++d)
                *(uint4*)&img[buf][img_sel][img_base4(lc + d, kp0)] =
                    make_uint4(pwq[d][0], pwq[d][1], pwq[d][2], pwq[d][3]);
            if (tile == 1) {
                #pragma unroll
                for (int it = 0; it < 4; ++it) {
                    s1r[0] += f0[it].x + f1[it].x; s2r[0] += f0[it].x * f0[it].x + f1[it].x * f1[it].x;
                    s1r[1] += f0[it].y + f1[it].y; s2r[1] += f0[it].y * f0[it].y + f1[it].y * f1[it].y;
                    s1r[2] += f0[it].z + f1[it].z; s2r[2] += f0[it].z * f0[it].z + f1[it].z * f1[it].z;
                    s1r[3] += f0[it].w + f1[it].w; s2r[3] += f0[it].w * f0[it].w + f1[it].w * f1[it].w;
                }
            }
        } else {
            unsigned pwq[4][2];
            #pragma unroll
            for (int it = 0; it < 2; ++it) {
                pwq[0][it] = pack_bf16(f0[it].x, f1[it].x);
                pwq[1][it] = pack_bf16(f0[it].y, f1[it].y);
                pwq[2][it] = pack_bf16(f0[it].z, f1[it].z);
                pwq[3][it] = pack_bf16(f0[it].w, f1[it].w);
            }
            #pragma unroll
            for (int d = 0; d < 4; ++d)
                *(uint2*)&img[buf][0][img_base2(lc + d, kp0)] =
                    make_uint2(pwq[d][0], pwq[d][1]);
        }
    };
    auto frag = [&](int buf, int sel, int col, int kd) -> bf16x8 {
        return *(const bf16x8*)&img[buf][sel][img_base4(col, kd)];
    };

    const int bch = diag ? 0 : 1;
    if (sb < se) {
        load_regs(sb);
        pack_store(0);
        __syncthreads();
        for (int s = sb; s < se; ++s) {
            const int buf = (s - sb) & 1;
            const bool more = (s + 1 < se);
            if (more) load_regs(s + 1);      // in flight across MFMAs
            #pragma unroll
            for (int h = 0; h < 2; ++h) {
                bf16x8 a[2], b[2];
                #pragma unroll
                for (int i = 0; i < 2; ++i) {
                    a[i] = frag(buf, 0,   wr * 64 + i * 32 + cg, h * 8 + q * 4);
                    b[i] = frag(buf, bch, wc * 64 + i * 32 + cg, h * 8 + q * 4);
                }
                acc[0][0] = __builtin_amdgcn_mfma_f32_32x32x16_bf16(a[0], b[0], acc[0][0], 0, 0, 0);
                acc[0][1] = __builtin_amdgcn_mfma_f32_32x32x16_bf16(a[0], b[1], acc[0][1], 0, 0, 0);
                acc[1][0] = __builtin_amdgcn_mfma_f32_32x32x16_bf16(a[1], b[0], acc[1][0], 0, 0, 0);
                acc[1][1] = __builtin_amdgcn_mfma_f32_32x32x16_bf16(a[1], b[1], acc[1][1], 0, 0, 0);
            }
            if (more) pack_store(buf ^ 1);   // other buffer: safe vs readers of buf
            __syncthreads();
        }
    }

    // split-K partial out (plain stores)
    float* gp = ws + WS_GPART + (size_t)split * GP_PER_SPLIT
              + ((size_t)tile * C * 2 + cls * 2 + inp) * GP_TILE;
    #pragma unroll
    for (int i = 0; i < 2; ++i)
        #pragma unroll
        for (int j = 0; j < 2; ++j)
            #pragma unroll
            for (int r = 0; r < 16; ++r) {
                const int row = wr * 64 + i * 32 + (r & 3) + 8 * (r >> 2) + 4 * q;
                const int col = wc * 64 + j * 32 + cg;
                gp[row * 128 + col] = acc[i][j][r];
            }

    if (tile == 1) {
        const int c0 = img_sel * 128 + lc;
        #pragma unroll
        for (int d = 0; d < 4; ++d) {
            atomicAdd(&sstats[c0 + d],       s1r[d]);
            atomicAdd(&sstats[256 + c0 + d], s2r[d]);
        }
        __syncthreads();
        const size_t base = (((size_t)split * C + cls) * 2 + inp) * 512;
        ws[WS_PSUM + base + t]       = sstats[t];
        ws[WS_PSUM + base + 256 + t] = sstats[256 + t];
    }
}

// Fold per-split stat partials into class stats.
__global__ __launch_bounds__(256) void k_reduce2(float* __restrict__ ws) {
    const int t = threadIdx.x;
    const int c = blockIdx.x;
    const int stat = blockIdx.y & 1, inp = blockIdx.y >> 1;
    float acc = 0.f;
    #pragma unroll
    for (int sp = 0; sp < NSPLIT; ++sp)
        acc += ws[WS_PSUM + (((size_t)sp * C + c) * 2 + inp) * 512 + stat * 256 + t];
    const int base = stat ? (inp ? WS_SQ_B : WS_SQ_A)
                          : (inp ? WS_SUMS_B : WS_SUMS_A);
    ws[base + c * D + t] = acc;
}

// Sum split partials, form cov, per-block cov^2 partial (k-split x8 for BW).
__global__ __launch_bounds__(256) void k_cov(const int* __restrict__ counts,
                                             float* __restrict__ ws) {
    const int t = threadIdx.x;
    const int tile = blockIdx.x / KC, k0 = blockIdx.x % KC;
    const int tx = tile >> 1, ty = (tile + 1) >> 1;
    const int cls = blockIdx.y, inp = blockIdx.z;
    const int cnt = counts[cls];
    const float fc = (float)cnt;
    const float cinv = 1.f / fc, uinv = 1.f / (fc - 1.f);
    const float wgt = (tx == ty) ? 1.f : 2.f;
    const int cm0 = tx * 128, cn0 = ty * 128;
    __shared__ float M[D];
    const float* sums = ws + (inp ? WS_SUMS_B : WS_SUMS_A) + cls * D;
    M[t] = sums[t] * cinv;
    __syncthreads();

    const float* gp0 = ws + WS_GPART + ((size_t)tile * C * 2 + cls * 2 + inp) * GP_TILE;
    float local = 0.f;
    #pragma unroll
    for (int kk = 0; kk < 64 / KC; ++kk) {
        const int e = (k0 * (64 / KC) + kk) * 256 + t;
        float g = 0.f;
        #pragma unroll
        for (int s = 0; s < NSPLIT; ++s)
            g += gp0[(size_t)s * GP_PER_SPLIT + e];
        const int row = e >> 7, col = e & 127;
        const int gm = cm0 + row, gn = cn0 + col;
        const float cov = (g - fc * M[gm] * M[gn]) * uinv;
        if (gm != gn) local += wgt * cov * cov;
    }
    for (int o = 32; o > 0; o >>= 1) local += __shfl_down(local, o, 64);
    __shared__ float red[4];
    if ((t & 63) == 0) red[t >> 6] = local;
    __syncthreads();
    if (t == 0)
        ws[WS_COVP + (((size_t)inp * C + cls) * 3 + tile) * KC + k0] =
            red[0] + red[1] + red[2] + red[3];
}

// ---------------- fallback (tiny ws): round-2 kernels ----------------
__global__ __launch_bounds__(256) void k_stats(const float* __restrict__ za,
                                               const float* __restrict__ zb,
                                               const int* __restrict__ labels,
                                               float* __restrict__ ws) {
    const int t = threadIdx.x;
    __shared__ float S[4][C * D];
    __shared__ int lab[512];
    for (int i = t; i < 4 * C * D; i += 256) ((float*)S)[i] = 0.f;
    const int r0 = blockIdx.x * 512;
    for (int i = t; i < 512; i += 256) lab[i] = labels[r0 + i];
    __syncthreads();
    float invp = 0.f;
    #pragma unroll 4
    for (int rr = 0; rr < 512; ++rr) {
        const int l = lab[rr];
        const float a = za[(size_t)(r0 + rr) * D + t];
        const float b = zb[(size_t)(r0 + rr) * D + t];
        const float dd = a - b;
        invp += dd * dd;
        S[0][l * D + t] += a;
        S[1][l * D + t] += a * a;
        S[2][l * D + t] += b;
        S[3][l * D + t] += b * b;
    }
    __syncthreads();
    #pragma unroll
    for (int c = 0; c < C; ++c) {
        atomicAdd(&ws[WS_SUMS_A + c * D + t], S[0][c * D + t]);
        atomicAdd(&ws[WS_SQ_A   + c * D + t], S[1][c * D + t]);
        atomicAdd(&ws[WS_SUMS_B + c * D + t], S[2][c * D + t]);
        atomicAdd(&ws[WS_SQ_B   + c * D + t], S[3][c * D + t]);
    }
    for (int o = 32; o > 0; o >>= 1) invp += __shfl_down(invp, o, 64);
    if ((t & 63) == 0) atomicAdd(&ws[WS_INV], invp);
}

#define STR 20
#define KB 32
__global__ __launch_bounds__(256) void k_gram_slow(const float* __restrict__ za,
                                                   const float* __restrict__ zb,
                                                   const int* __restrict__ perm,
                                                   const int* __restrict__ counts,
                                                   float* __restrict__ ws) {
    const int t = threadIdx.x;
    const int tile = blockIdx.x;
    const int tx = tile >> 1, ty = (tile + 1) >> 1;
    const int cls = blockIdx.y;
    const int inp = blockIdx.z;
    const float* X = inp ? zb : za;
    const float* sums = ws + (inp ? WS_SUMS_B : WS_SUMS_A) + cls * D;
    int offs = 0;
    for (int c = 0; c < cls; ++c) offs += counts[c];
    const int cnt = counts[cls];
    const int cm0 = tx * 128, cn0 = ty * 128;
    __shared__ __align__(16) unsigned lds[2][256 * STR];
    const int p = t >> 5, cq = t & 31;
    const int lane = t & 63, w = t >> 6;
    const int wr = w & 1, wc = w >> 1;
    const int cg = lane & 31, q = lane >> 5;
    f32x16 acc[2][2];
    #pragma unroll
    for (int i = 0; i < 2; ++i)
        #pragma unroll
        for (int j = 0; j < 2; ++j) acc[i][j] = 0.0f;
    const int nsteps = (cnt + KB - 1) / KB;
    auto stage = [&](int buf, int k0) {
        #pragma unroll
        for (int ch = 0; ch < 2; ++ch) {
            const int gc = (ch ? cn0 : cm0) + 4 * cq;
            #pragma unroll
            for (int sub = 0; sub < 2; ++sub) {
                const int rr = sub * 16 + 2 * p;
                const int r0 = k0 + rr, r1 = r0 + 1;
                float4 v0 = make_float4(0.f, 0.f, 0.f, 0.f), v1 = v0;
                if (r0 < cnt) v0 = *(const float4*)(X + (size_t)perm[offs + r0] * D + gc);
                if (r1 < cnt) v1 = *(const float4*)(X + (size_t)perm[offs + r1] * D + gc);
                unsigned* dst = &lds[buf][(ch * 128 + 4 * cq) * STR + (rr >> 1)];
                dst[0 * STR] = pack_bf16(v0.x, v1.x);
                dst[1 * STR] = pack_bf16(v0.y, v1.y);
                dst[2 * STR] = pack_bf16(v0.z, v1.z);
                dst[3 * STR] = pack_bf16(v0.w, v1.w);
            }
        }
    };
    auto frag = [&](int buf, int colbase, int h) -> bf16x8 {
        return *(const bf16x8*)&lds[buf][(colbase + cg) * STR + h * 8 + q * 4];
    };
    stage(0, 0);
    for (int s = 0; s < nsteps; ++s) {
        __syncthreads();
        const int buf = s & 1;
        if (s + 1 < nsteps) stage(buf ^ 1, (s + 1) * KB);
        #pragma unroll
        for (int h = 0; h < 2; ++h) {
            bf16x8 a0 = frag(buf, wr * 64, h);
            bf16x8 a1 = frag(buf, wr * 64 + 32, h);
            bf16x8 b0 = frag(buf, 128 + wc * 64, h);
            bf16x8 b1 = frag(buf, 128 + wc * 64 + 32, h);
            acc[0][0] = __builtin_amdgcn_mfma_f32_32x32x16_bf16(a0, b0, acc[0][0], 0, 0, 0);
            acc[0][1] = __builtin_amdgcn_mfma_f32_32x32x16_bf16(a0, b1, acc[0][1], 0, 0, 0);
            acc[1][0] = __builtin_amdgcn_mfma_f32_32x32x16_bf16(a1, b0, acc[1][0], 0, 0, 0);
            acc[1][1] = __builtin_amdgcn_mfma_f32_32x32x16_bf16(a1, b1, acc[1][1], 0, 0, 0);
        }
    }
    const float fc = (float)cnt;
    const float cinv = 1.f / fc, uinv = 1.f / (fc - 1.f);
    const float wgt = (tx == ty) ? 1.f : 2.f;
    float local = 0.f;
    #pragma unroll
    for (int i = 0; i < 2; ++i) {
        #pragma unroll
        for (int j = 0; j < 2; ++j) {
            const int gn = cn0 + wc * 64 + j * 32 + (lane & 31);
            const float mn = sums[gn] * cinv;
            #pragma unroll
            for (int r = 0; r < 16; ++r) {
                const int row = (r & 3) + 8 * (r >> 2) + 4 * q;
                const int gm = cm0 + wr * 64 + i * 32 + row;
                const float cov = (acc[i][j][r] - fc * (sums[gm] * cinv) * mn) * uinv;
                if (gm != gn) local += wgt * cov * cov;
            }
        }
    }
    for (int o = 32; o > 0; o >>= 1) local += __shfl_down(local, o, 64);
    if (lane == 0) atomicAdd(&ws[WS_COV], local);
}

__global__ __launch_bounds__(256) void k_final(const float* __restrict__ ws,
                                               float* __restrict__ out,
                                               int fast) {
    __shared__ float M[C * D];
    __shared__ float redv[4], redi[4], redc[4], redp[4];
    const int t = threadIdx.x;
    const int* counts = (const int*)ws + WS_COUNTS;

    float vsum = 0.f;
    for (int idx = t; idx < 2 * C * D; idx += 256) {
        const int inp = idx >> 12;
        const int cd = idx & 4095;
        const int c = cd >> 8;
        const float cnt = (float)counts[c];
        const float s  = ws[(inp ? WS_SUMS_B : WS_SUMS_A) + cd];
        const float sq = ws[(inp ? WS_SQ_B   : WS_SQ_A)   + cd];
        const float mean = s / cnt;
        const float var = (sq - cnt * mean * mean) / (cnt - 1.f);
        vsum += fmaxf(1.f - sqrtf(var + 1e-4f), 0.f);
    }
    float isum, csum;
    if (fast) {
        isum = ws[WS_INVP + t] + ws[WS_INVP + 256 + t];
        csum = ws[WS_COVP + t] + ws[WS_COVP + 256 + t] + ws[WS_COVP + 512 + t];
    } else {
        isum = (t == 0) ? ws[WS_INV] : 0.f;
        csum = (t == 0) ? ws[WS_COV] : 0.f;
    }
    for (int cd = t; cd < C * D; cd += 256) {
        const int c = cd >> 8;
        const float cnt = (float)counts[c];
        M[cd] = 0.5f * (ws[WS_SUMS_A + cd] + ws[WS_SUMS_B + cd]) / cnt;
    }
    for (int o = 32; o > 0; o >>= 1) {
        vsum += __shfl_down(vsum, o, 64);
        isum += __shfl_down(isum, o, 64);
        csum += __shfl_down(csum, o, 64);
    }
    if ((t & 63) == 0) {
        redv[t >> 6] = vsum; redi[t >> 6] = isum; redc[t >> 6] = csum;
    }
    __syncthreads();

    const int wv = t >> 6, ln = t & 63;
    float psum = 0.f;
    int p = 0;
    for (int i = 0; i < C; ++i) {
        for (int j = i + 1; j < C; ++j, ++p) {
            if ((p & 3) != wv) continue;
            float d2 = 0.f;
            #pragma unroll
            for (int d = ln; d < D; d += 64) {
                const float df = M[i * D + d] - M[j * D + d];
                d2 += df * df;
            }
            for (int o = 32; o > 0; o >>= 1) d2 += __shfl_down(d2, o, 64);
            if (ln == 0) {
                const float dist = sqrtf(d2);
                const float r = fmaxf(50.f - dist, 0.f);
                psum += r * r;
            }
        }
    }
    if (ln == 0) redp[wv] = psum;
    __syncthreads();

    if (t == 0) {
        const float var_loss = (redv[0] + redv[1] + redv[2] + redv[3]) / 8192.f;
        const float class_loss = (redp[0] + redp[1] + redp[2] + redp[3]) / 120.f;
        const float inv_loss = (redi[0] + redi[1] + redi[2] + redi[3]) / (float)(N_ROWS * D);
        const float cov_loss = 0.5f * (redc[0] + redc[1] + redc[2] + redc[3]) / (float)(C * D);
        out[0] = 25.f * inv_loss + 25.f * var_loss + 1.f * cov_loss + 50.f * class_loss;
    }
}

extern "C" void kernel_launch(void* const* d_in, const int* in_sizes, int n_in,
                              void* d_out, int out_size, void* d_ws, size_t ws_size,
                              hipStream_t stream) {
    const float* za = (const float*)d_in[0];
    const float* zb = (const float*)d_in[1];
    const int* labels = (const int*)d_in[2];
    float* out = (float*)d_out;
    float* ws = (float*)d_ws;
    int* wsi = (int*)d_ws;

    hipMemsetAsync(d_ws, 0, WS_ZERO_FLOATS * sizeof(float), stream);
    k_hist<<<64, 512, 0, stream>>>(labels, wsi + WS_COUNTS);
    k_scan<<<1, 64, 0, stream>>>(wsi + WS_COUNTS, wsi + WS_CURSOR,
                                 wsi + WS_POFFP, wsi + WS_EOFF);
    k_scatter<<<64, 512, 0, stream>>>(labels, wsi + WS_CURSOR, wsi + WS_PERM);

    if (ws_size >= NEED_A) {
        k_inv<<<512, 256, 0, stream>>>(za, zb, ws);
        k_gram5<<<dim3(3 * NSPLIT, C, 2), 256, 0, stream>>>(
            za, zb, wsi + WS_PERM, wsi + WS_COUNTS, wsi + WS_POFFP,
            wsi + WS_EOFF, ws);
        k_reduce2<<<dim3(C, 4), 256, 0, stream>>>(ws);
        k_cov<<<dim3(3 * KC, C, 2), 256, 0, stream>>>(wsi + WS_COUNTS, ws);
        k_final<<<1, 256, 0, stream>>>(ws, out, 1);
    } else {
        k_stats<<<64, 256, 0, stream>>>(za, zb, labels, ws);
        k_gram_slow<<<dim3(3, C, 2), 256, 0, stream>>>(za, zb, wsi + WS_PERM,
                                                       wsi + WS_COUNTS, ws);
        k_final<<<1, 256, 0, stream>>>(ws, out, 0);
    }
}